// Round 9
// baseline (268.679 us; speedup 1.0000x reference)
//
#include <hip/hip_runtime.h>
#include <math.h>

#define DIMC  512
#define HEADS 8
#define HD    64
#define NPIX  16384   // 128*128
#define LTOK  256     // 16*16
#define BATCH 2
#define WIMG  128
#define KVK   32768   // 512*8*8
#define EPSB  1e-8f
#define SCALEF 0.125f // 64^-0.5
#define SPLITK 16
#define KCHUNK (KVK / SPLITK)   // 2048

typedef unsigned short ushort_t;
typedef unsigned int uint_t;
using bf16x8 = __attribute__((ext_vector_type(8))) __bf16;
using f32x4  = __attribute__((ext_vector_type(4))) float;

__device__ __forceinline__ ushort_t f2bf(float f) {
    union { float f; unsigned u; } v; v.f = f;
    unsigned r = v.u + 0x7FFFu + ((v.u >> 16) & 1u);
    return (ushort_t)(r >> 16);
}
__device__ __forceinline__ uint_t pk2bf(float a, float b) {
    return (uint_t)f2bf(a) | ((uint_t)f2bf(b) << 16);
}
// async global->LDS, 16B per lane; lds base must be wave-uniform
__device__ __forceinline__ void gl16(const void* g, void* l) {
    __builtin_amdgcn_global_load_lds(
        (const __attribute__((address_space(1))) unsigned int*)g,
        (__attribute__((address_space(3))) unsigned int*)l, 16, 0, 0);
}

// ---------------- mask downsample (avg pool 8x8) ----------------
__global__ void k_maskdown(const float* __restrict__ mask, float* __restrict__ md) {
    int b = blockIdx.x;
    int l = threadIdx.x;
    int hr = l >> 4, wr = l & 15;
    const float* mp = mask + (size_t)b * NPIX;
    float s = 0.f;
#pragma unroll
    for (int i = 0; i < 8; ++i)
#pragma unroll
        for (int j = 0; j < 8; ++j)
            s += mp[(hr * 8 + i) * WIMG + wr * 8 + j];
    md[b * LTOK + l] = s * (1.f / 64.f);
}

// ---------------- x [b][c][n] f32 -> xt [b][n][c] bf16, vectorized stores ------
__global__ __launch_bounds__(256) void k_xt(const float* __restrict__ x, ushort_t* __restrict__ xt) {
    __shared__ float t[64][65];
    int b = blockIdx.z, c0 = blockIdx.y * 64, n0 = blockIdx.x * 64;
    int tn = threadIdx.x & 63, tc = threadIdx.x >> 6;
    const float* xb = x + ((size_t)b * DIMC + c0) * NPIX + n0;
#pragma unroll
    for (int p = 0; p < 16; ++p)
        t[tc + p * 4][tn] = xb[(size_t)(tc + p * 4) * NPIX + tn];
    __syncthreads();
    ushort_t* xtb = xt + ((size_t)b * NPIX + n0) * DIMC + c0;
    int tc4 = threadIdx.x & 15, ng = threadIdx.x >> 4;
#pragma unroll
    for (int p = 0; p < 4; ++p) {
        int nl = ng + p * 16;
        ushort4 v;
        v.x = f2bf(t[4 * tc4 + 0][nl]);
        v.y = f2bf(t[4 * tc4 + 1][nl]);
        v.z = f2bf(t[4 * tc4 + 2][nl]);
        v.w = f2bf(t[4 * tc4 + 3][nl]);
        *(ushort4*)&xtb[(size_t)nl * DIMC + 4 * tc4] = v;
    }
}

// ---------------- Wq + Wo f32 -> bf16, one launch ----------------
__global__ void k_cvt2(const float* __restrict__ a, const float* __restrict__ b,
                       ushort_t* __restrict__ da, ushort_t* __restrict__ db) {
    int i = blockIdx.x * 256 + threadIdx.x;    // grid 2048 -> [0, 524288)
    if (i < 262144) da[i] = f2bf(a[i]);
    else            db[i - 262144] = f2bf(b[i - 262144]);
}

// ================= MFMA GEMM (1x1 convs), 128x128 tile, BK=64, dbuf prefetch =================
// T2 swizzle, pre-swizzled-source form: LDS dest linear, global k-block XORed
// with (row&7) at stage, fragment read XORs the slot index the same way.
template<int EPI>
__global__ __launch_bounds__(256) void k_gemm_qo(
    const ushort_t* __restrict__ A, long sA,
    const ushort_t* __restrict__ B, long sB,
    void* __restrict__ Yv) {
    __shared__ ushort_t Asm[2][128 * 64];
    __shared__ ushort_t Bsm[2][128 * 64];
    const int tid = threadIdx.x;
    const int w = tid >> 6, lane = tid & 63;
    const int wm = w >> 1, wn = w & 1;
    const int lr = lane & 15, lg = lane >> 4;
    const int bz = blockIdx.z;
    const int m0 = blockIdx.y * 128, c0 = blockIdx.x * 128;
    const ushort_t* Ab = A + (size_t)bz * sA;
    const ushort_t* Bb = B + (size_t)bz * sB;

    f32x4 acc[4][4];
    const f32x4 zz = {0.f, 0.f, 0.f, 0.f};
#pragma unroll
    for (int i = 0; i < 4; ++i)
#pragma unroll
        for (int j = 0; j < 4; ++j) acc[i][j] = zz;

#define STAGE_QO(buf, k0) do {                                               \
    _Pragma("unroll")                                                        \
    for (int r = 0; r < 4; ++r) {                                            \
        int slot = r * 256 + tid;                                            \
        int m = slot >> 3, kb = slot & 7;                                    \
        int kbs = kb ^ (m & 7);                                              \
        gl16(Ab + (size_t)(m0 + m) * DIMC + (k0) + kbs * 8,                  \
             &Asm[buf][(size_t)(r * 256 + w * 64) * 8]);                     \
    }                                                                        \
    _Pragma("unroll")                                                        \
    for (int r = 0; r < 4; ++r) {                                            \
        int slot = r * 256 + tid;                                            \
        int m = slot >> 3, kb = slot & 7;                                    \
        int kbs = kb ^ (m & 7);                                              \
        gl16(Bb + (size_t)(c0 + m) * DIMC + (k0) + kbs * 8,                  \
             &Bsm[buf][(size_t)(r * 256 + w * 64) * 8]);                     \
    }                                                                        \
} while (0)

    STAGE_QO(0, 0);
    __syncthreads();
    int cur = 0;
#pragma unroll 1
    for (int t = 0; t < 8; ++t) {
        if (t < 7) STAGE_QO(cur ^ 1, (t + 1) * 64);
#pragma unroll
        for (int kk = 0; kk < 2; ++kk) {
            bf16x8 af[4], bfr[4];
#pragma unroll
            for (int i = 0; i < 4; ++i) {
                int row = wm * 64 + i * 16 + lr;
                af[i] = *(const bf16x8*)&Asm[cur][(size_t)(row * 8 + ((kk * 4 + lg) ^ (row & 7))) * 8];
            }
#pragma unroll
            for (int j = 0; j < 4; ++j) {
                int row = wn * 64 + j * 16 + lr;
                bfr[j] = *(const bf16x8*)&Bsm[cur][(size_t)(row * 8 + ((kk * 4 + lg) ^ (row & 7))) * 8];
            }
#pragma unroll
            for (int i = 0; i < 4; ++i)
#pragma unroll
                for (int j = 0; j < 4; ++j)
                    acc[i][j] = __builtin_amdgcn_mfma_f32_16x16x32_bf16(af[i], bfr[j], acc[i][j], 0, 0, 0);
        }
        if (t < 7) {
            __syncthreads();   // drains vmcnt(0): prefetch flew during the MFMAs above
            cur ^= 1;
        }
    }
#undef STAGE_QO

    if (EPI == 0) {
        ushort_t* q = (ushort_t*)Yv + (size_t)bz * ((size_t)NPIX * DIMC);
#pragma unroll
        for (int i = 0; i < 4; ++i) {
            int d0 = m0 + wm * 64 + i * 16 + lg * 4;
#pragma unroll
            for (int j = 0; j < 4; ++j) {
                int n = c0 + wn * 64 + j * 16 + lr;
                ushort4 v;
                v.x = f2bf(acc[i][j][0]); v.y = f2bf(acc[i][j][1]);
                v.z = f2bf(acc[i][j][2]); v.w = f2bf(acc[i][j][3]);
                *(ushort4*)&q[(size_t)n * DIMC + d0] = v;
            }
        }
    } else {
        float* O = (float*)Yv + (size_t)bz * ((size_t)DIMC * NPIX);
#pragma unroll
        for (int i = 0; i < 4; ++i) {
            int n0r = m0 + wm * 64 + i * 16 + lg * 4;
#pragma unroll
            for (int j = 0; j < 4; ++j) {
                int o = c0 + wn * 64 + j * 16 + lr;
                *(f32x4*)&O[(size_t)o * NPIX + n0r] = acc[i][j];
            }
        }
    }
}

// ================= MFMA kv conv: direct from f32 x and Wkv =================
// k-order = Wkv natural flat order (k = c*64 + ii*8 + jj), so A-frag =
// Wkv[o*KVK + k] and B-frag = x[c*NPIX + (hr*8+ii)*128 + wr*8 + jj] are both
// 32B-contiguous f32. Reg-stage (T14 issue-early/write-late) + cvt to bf16 +
// swizzled ds_write (T2 on the write side). Single 32KB LDS buffer.
// Grid 512 1-D, XCD-grouped: 16 blocks of one (b,ks) chunk share an XCD L2.
__global__ __launch_bounds__(256) void k_convkv_mfma(
    const float* __restrict__ x, const float* __restrict__ Wkv,
    float* __restrict__ part) {
    __shared__ ushort_t Asm[128 * 64];   // 16KB, [row][8 slots of 16B]
    __shared__ ushort_t Bsm[128 * 64];   // 16KB
    const int tid = threadIdx.x;
    const int w = tid >> 6, lane = tid & 63;
    const int wm = w >> 1, wn = w & 1;
    const int lr = lane & 15, lg = lane >> 4;
    const int f = blockIdx.x;
    const int xcd = f & 7, idx = f >> 3;
    const int z = (idx >> 4) * 8 + xcd;      // 0..31, 4 z per XCD
    const int inner = idx & 15;
    const int m0 = (inner >> 1) * 128, n0 = (inner & 1) * 128;
    const int b = z >> 4, ks = z & 15;
    const float* xb = x + (size_t)b * DIMC * NPIX;
    const int kbeg = ks * KCHUNK;

    // per-slot constants (slot = r*256+tid; row = slot>>3, kb = slot&7)
    const int srow = tid >> 3, skb = tid & 7;          // +32*r rows per pass
    f32x4 acc[4][4];
    const f32x4 zz = {0.f, 0.f, 0.f, 0.f};
#pragma unroll
    for (int i = 0; i < 4; ++i)
#pragma unroll
        for (int j = 0; j < 4; ++j) acc[i][j] = zz;

    float4 ra[4][2], rb[4][2];

#define LOAD_KV(k0) do {                                                     \
    _Pragma("unroll")                                                        \
    for (int r = 0; r < 4; ++r) {                                            \
        int m = srow + 32 * r;                                               \
        const float* pa = Wkv + (size_t)(m0 + m) * KVK + (k0) + skb * 8;     \
        ra[r][0] = *(const float4*)pa;                                       \
        ra[r][1] = *(const float4*)(pa + 4);                                 \
        int l = n0 + m, hr = l >> 4, wr = l & 15;                            \
        const float* pb = xb + (size_t)((k0) >> 6) * NPIX                    \
                          + (hr * 8 + skb) * WIMG + wr * 8;                  \
        rb[r][0] = *(const float4*)pb;                                       \
        rb[r][1] = *(const float4*)(pb + 4);                                 \
    }                                                                        \
} while (0)

#define WRITE_KV() do {                                                      \
    _Pragma("unroll")                                                        \
    for (int r = 0; r < 4; ++r) {                                            \
        int m = srow + 32 * r;                                               \
        int off = (m * 8 + (skb ^ (m & 7))) * 8;                             \
        uint4 va, vb;                                                        \
        va.x = pk2bf(ra[r][0].x, ra[r][0].y);                                \
        va.y = pk2bf(ra[r][0].z, ra[r][0].w);                                \
        va.z = pk2bf(ra[r][1].x, ra[r][1].y);                                \
        va.w = pk2bf(ra[r][1].z, ra[r][1].w);                                \
        vb.x = pk2bf(rb[r][0].x, rb[r][0].y);                                \
        vb.y = pk2bf(rb[r][0].z, rb[r][0].w);                                \
        vb.z = pk2bf(rb[r][1].x, rb[r][1].y);                                \
        vb.w = pk2bf(rb[r][1].z, rb[r][1].w);                                \
        *(uint4*)&Asm[off] = va;                                             \
        *(uint4*)&Bsm[off] = vb;                                             \
    }                                                                        \
} while (0)

    LOAD_KV(kbeg);
    WRITE_KV();
    __syncthreads();
#pragma unroll 1
    for (int t = 0; t < KCHUNK / 64; ++t) {
        if (t < KCHUNK / 64 - 1) LOAD_KV(kbeg + (t + 1) * 64);  // flies over MFMAs
#pragma unroll
        for (int kk = 0; kk < 2; ++kk) {
            bf16x8 af[4], bfr[4];
#pragma unroll
            for (int i = 0; i < 4; ++i) {
                int row = wm * 64 + i * 16 + lr;
                af[i] = *(const bf16x8*)&Asm[(size_t)(row * 8 + ((kk * 4 + lg) ^ (row & 7))) * 8];
            }
#pragma unroll
            for (int j = 0; j < 4; ++j) {
                int row = wn * 64 + j * 16 + lr;
                bfr[j] = *(const bf16x8*)&Bsm[(size_t)(row * 8 + ((kk * 4 + lg) ^ (row & 7))) * 8];
            }
#pragma unroll
            for (int i = 0; i < 4; ++i)
#pragma unroll
                for (int j = 0; j < 4; ++j)
                    acc[i][j] = __builtin_amdgcn_mfma_f32_16x16x32_bf16(af[i], bfr[j], acc[i][j], 0, 0, 0);
        }
        __syncthreads();                    // all waves done reading buffer
        if (t < KCHUNK / 64 - 1) {
            WRITE_KV();                     // vmcnt drained here by the use
            __syncthreads();                // buffer refilled
        }
    }
#undef LOAD_KV
#undef WRITE_KV

    float* P = part + (size_t)z * (LTOK * 1024);
#pragma unroll
    for (int i = 0; i < 4; ++i) {
        int o0 = m0 + wm * 64 + i * 16 + lg * 4;
#pragma unroll
        for (int j = 0; j < 4; ++j) {
            int l = n0 + wn * 64 + j * 16 + lr;
            *(f32x4*)&P[(size_t)l * 1024 + o0] = acc[i][j];
        }
    }
}

// reduce partials -> kt bf16 [b][h][l][64], vt bf16 [b][h][d][256]
__global__ void k_kvreduce(const float* __restrict__ part,
                           ushort_t* __restrict__ kt, ushort_t* __restrict__ vt) {
    int idx = blockIdx.x * 256 + threadIdx.x;   // [0, 2*256*1024)
    int o = idx & 1023;
    int rest = idx >> 10;
    int l = rest & 255, b = rest >> 8;
    float s = 0.f;
#pragma unroll
    for (int ks = 0; ks < SPLITK; ++ks)
        s += part[(size_t)(b * SPLITK + ks) * (LTOK * 1024) + (size_t)l * 1024 + o];
    int h = (o >> 6) & 7, d = o & 63;
    if (o < 512)
        kt[(((size_t)b * 8 + h) * 256 + l) * 64 + d] = f2bf(s);
    else
        vt[(((size_t)b * 8 + h) * 64 + d) * 256 + l] = f2bf(s);
}

// ================= MFMA fused attention (R6 proven version) =================
__global__ __launch_bounds__(256, 2) void k_attn_mfma(
    const ushort_t* __restrict__ qbf, const ushort_t* __restrict__ kt,
    const ushort_t* __restrict__ vt, const float* __restrict__ mask,
    const float* __restrict__ md, ushort_t* __restrict__ obuf) {
    __shared__ ushort_t Qs[128 * 64];   // 16KB, rows 128B, 8 slots of 16B, XOR-swizzled
    __shared__ ushort_t Ks[256 * 64];   // 32KB
    __shared__ ushort_t Vs[64 * 256];   // 32KB, rows 512B, 32 slots

    const int tid = threadIdx.x;
    const int w = tid >> 6, lane = tid & 63;
    const int g = lane >> 4, ln = lane & 15;
    const int bh = blockIdx.y, b = bh >> 3, h = bh & 7;
    const int bb = bh & 1;              // bias batch quirk: (b*8+h) % 2
    const int n0 = blockIdx.x * 128;

    {
        const ushort_t* src = qbf + ((size_t)b * NPIX + n0) * DIMC + h * 64;
#pragma unroll
        for (int p = 0; p < 4; ++p) {
            int id = p * 256 + tid;
            int r = id >> 3, s = id & 7;
            uint4 v = *(const uint4*)(src + (size_t)r * DIMC + s * 8);
            *(uint4*)&Qs[(r * 8 + (s ^ (r & 7))) * 8] = v;
        }
    }
    {
        const ushort_t* src = kt + (size_t)bh * 256 * 64;
#pragma unroll
        for (int p = 0; p < 8; ++p) {
            int id = p * 256 + tid;
            int r = id >> 3, s = id & 7;
            uint4 v = *(const uint4*)(src + r * 64 + s * 8);
            *(uint4*)&Ks[(r * 8 + (s ^ (r & 7))) * 8] = v;
        }
    }
    {
        const ushort_t* src = vt + (size_t)bh * 64 * 256;
#pragma unroll
        for (int p = 0; p < 8; ++p) {
            int id = p * 256 + tid;
            int r = id >> 5, s = id & 31;
            uint4 v = *(const uint4*)(src + r * 256 + s * 8);
            *(uint4*)&Vs[(r * 32 + (s ^ (r & 7))) * 8] = v;
        }
    }
    __syncthreads();

    f32x4 acc[2][16];
    const f32x4 zz = {0.f, 0.f, 0.f, 0.f};
#pragma unroll
    for (int nf = 0; nf < 2; ++nf)
#pragma unroll
        for (int f = 0; f < 16; ++f) acc[nf][f] = zz;

    bf16x8 qf[2][2];
#pragma unroll
    for (int nf = 0; nf < 2; ++nf)
#pragma unroll
        for (int kk = 0; kk < 2; ++kk) {
            int nl = 32 * w + nf * 16 + ln;
            qf[nf][kk] = *(const bf16x8*)&Qs[(nl * 8 + ((kk * 4 + g) ^ (nl & 7))) * 8];
        }
#pragma unroll
    for (int f = 0; f < 16; ++f) {
#pragma unroll
        for (int kk = 0; kk < 2; ++kk) {
            int l = f * 16 + ln;
            bf16x8 kf = *(const bf16x8*)&Ks[(l * 8 + ((kk * 4 + g) ^ (l & 7))) * 8];
            acc[0][f] = __builtin_amdgcn_mfma_f32_16x16x32_bf16(kf, qf[0][kk], acc[0][f], 0, 0, 0);
            acc[1][f] = __builtin_amdgcn_mfma_f32_16x16x32_bf16(kf, qf[1][kk], acc[1][f], 0, 0, 0);
        }
    }

    float inv[2];
    uint2 pb[2][16];
#pragma unroll
    for (int nf = 0; nf < 2; ++nf) {
        float mval = mask[(size_t)bb * NPIX + n0 + 32 * w + nf * 16 + ln];
        float mx = -1e30f;
#pragma unroll
        for (int f = 0; f < 16; ++f) {
            float4 md4 = *(const float4*)&md[bb * LTOK + f * 16 + g * 4];
            float s0 = (acc[nf][f][0] + __logf(mval * md4.x + EPSB)) * SCALEF;
            float s1 = (acc[nf][f][1] + __logf(mval * md4.y + EPSB)) * SCALEF;
            float s2 = (acc[nf][f][2] + __logf(mval * md4.z + EPSB)) * SCALEF;
            float s3 = (acc[nf][f][3] + __logf(mval * md4.w + EPSB)) * SCALEF;
            acc[nf][f][0] = s0; acc[nf][f][1] = s1;
            acc[nf][f][2] = s2; acc[nf][f][3] = s3;
            mx = fmaxf(mx, fmaxf(fmaxf(s0, s1), fmaxf(s2, s3)));
        }
        mx = fmaxf(mx, __shfl_xor(mx, 16));
        mx = fmaxf(mx, __shfl_xor(mx, 32));
        float sum = 0.f;
#pragma unroll
        for (int f = 0; f < 16; ++f) {
            float p0 = __expf(acc[nf][f][0] - mx);
            float p1 = __expf(acc[nf][f][1] - mx);
            float p2 = __expf(acc[nf][f][2] - mx);
            float p3 = __expf(acc[nf][f][3] - mx);
            sum += (p0 + p1) + (p2 + p3);
            pb[nf][f].x = pk2bf(p0, p1);
            pb[nf][f].y = pk2bf(p2, p3);
        }
        sum += __shfl_xor(sum, 16);
        sum += __shfl_xor(sum, 32);
        inv[nf] = 1.f / sum;
    }

    f32x4 acc2[2][4];
#pragma unroll
    for (int nf = 0; nf < 2; ++nf)
#pragma unroll
        for (int df = 0; df < 4; ++df) acc2[nf][df] = zz;

    const int srcLo = ((g & 1) << 5) + ln;
    const bool selHi = (g >> 1);
#pragma unroll
    for (int ks = 0; ks < 8; ++ks) {
        bf16x8 vf[4];
#pragma unroll
        for (int df = 0; df < 4; ++df) {
            int d = df * 16 + ln;
            vf[df] = *(const bf16x8*)&Vs[(d * 32 + ((ks * 4 + g) ^ (d & 7))) * 8];
        }
#pragma unroll
        for (int nf = 0; nf < 2; ++nf) {
            uint_t e0 = pb[nf][2 * ks].x,     e1 = pb[nf][2 * ks].y;
            uint_t o0 = pb[nf][2 * ks + 1].x, o1 = pb[nf][2 * ks + 1].y;
            uint_t lo0 = __shfl((int)e0, srcLo), lo1 = __shfl((int)e1, srcLo);
            uint_t lo0b = __shfl((int)o0, srcLo), lo1b = __shfl((int)o1, srcLo);
            uint_t hi0 = __shfl((int)e0, srcLo + 16), hi1 = __shfl((int)e1, srcLo + 16);
            uint_t hi0b = __shfl((int)o0, srcLo + 16), hi1b = __shfl((int)o1, srcLo + 16);
            union { uint_t u[4]; bf16x8 v; } bfr;
            bfr.u[0] = selHi ? lo0b : lo0;
            bfr.u[1] = selHi ? lo1b : lo1;
            bfr.u[2] = selHi ? hi0b : hi0;
            bfr.u[3] = selHi ? hi1b : hi1;
#pragma unroll
            for (int df = 0; df < 4; ++df)
                acc2[nf][df] = __builtin_amdgcn_mfma_f32_16x16x32_bf16(vf[df], bfr.v, acc2[nf][df], 0, 0, 0);
        }
    }

#pragma unroll
    for (int nf = 0; nf < 2; ++nf) {
        int n = n0 + 32 * w + nf * 16 + ln;
        ushort_t* op = obuf + ((size_t)b * NPIX + n) * DIMC + h * 64;
#pragma unroll
        for (int df = 0; df < 4; ++df) {
            ushort4 v;
            v.x = f2bf(acc2[nf][df][0] * inv[nf]);
            v.y = f2bf(acc2[nf][df][1] * inv[nf]);
            v.z = f2bf(acc2[nf][df][2] * inv[nf]);
            v.w = f2bf(acc2[nf][df][3] * inv[nf]);
            *(ushort4*)&op[df * 16 + g * 4] = v;
        }
    }
}

extern "C" void kernel_launch(void* const* d_in, const int* in_sizes, int n_in,
                              void* d_out, int out_size, void* d_ws, size_t ws_size,
                              hipStream_t stream) {
    const float* x    = (const float*)d_in[0];
    const float* mask = (const float*)d_in[1];
    const float* Wq   = (const float*)d_in[2];
    const float* Wkv  = (const float*)d_in[3];
    const float* Wo   = (const float*)d_in[4];
    float* out = (float*)d_out;

    char* ws = (char*)d_ws;
    float*    md   = (float*)(ws);                         // 4 KB
    ushort_t* xt   = (ushort_t*)(ws + 4096);               // 33.55 MB
    ushort_t* qbf  = (ushort_t*)(ws + 33558528);           // 33.55 MB (wkvp slot freed)
    ushort_t* ktb  = (ushort_t*)(ws + 100667392);          // 0.5 MB
    ushort_t* vtb  = ktb + 524288;                         // 0.5 MB
    ushort_t* wqb  = (ushort_t*)(ws + 102764544);          // 0.5 MB
    ushort_t* wob  = wqb + 262144;                         // 0.5 MB
    float*    part = (float*)(ws + 103813120);             // 33.55 MB
    ushort_t* aob  = (ushort_t*)part;                      // alias: written after kvreduce

    k_maskdown<<<dim3(BATCH), dim3(256), 0, stream>>>(mask, md);
    k_cvt2<<<dim3(2048), dim3(256), 0, stream>>>(Wq, Wo, wqb, wob);
    k_convkv_mfma<<<dim3(512), dim3(256), 0, stream>>>(x, Wkv, part);
    k_xt<<<dim3(NPIX / 64, DIMC / 64, BATCH), dim3(256), 0, stream>>>(x, xt);
    k_kvreduce<<<dim3(2048), dim3(256), 0, stream>>>(part, ktb, vtb);

    k_gemm_qo<0><<<dim3(NPIX / 128, DIMC / 128, BATCH), dim3(256), 0, stream>>>(
        wqb, 0L, xt, (long)NPIX * DIMC, qbf);

    k_attn_mfma<<<dim3(NPIX / 128, BATCH * HEADS), dim3(256), 0, stream>>>(
        qbf, ktb, vtb, mask, md, aob);

    k_gemm_qo<1><<<dim3(DIMC / 128, NPIX / 128, BATCH), dim3(256), 0, stream>>>(
        aob, (long)NPIX * DIMC, wob, 0L, out);
}

// Round 10
// 247.877 us; speedup vs baseline: 1.0839x; 1.0839x over previous
//
#include <hip/hip_runtime.h>
#include <math.h>

#define DIMC  512
#define HEADS 8
#define HD    64
#define NPIX  16384   // 128*128
#define LTOK  256     // 16*16
#define BATCH 2
#define WIMG  128
#define KVK   32768   // 512*8*8
#define EPSB  1e-8f
#define SCALEF 0.125f // 64^-0.5
#define SPLITK 16
#define KCHUNK (KVK / SPLITK)   // 2048

typedef unsigned short ushort_t;
typedef unsigned int uint_t;
using bf16x8 = __attribute__((ext_vector_type(8))) __bf16;
using f32x4  = __attribute__((ext_vector_type(4))) float;

__device__ __forceinline__ ushort_t f2bf(float f) {
    union { float f; unsigned u; } v; v.f = f;
    unsigned r = v.u + 0x7FFFu + ((v.u >> 16) & 1u);
    return (ushort_t)(r >> 16);
}
__device__ __forceinline__ uint_t pk2bf(float a, float b) {
    return (uint_t)f2bf(a) | ((uint_t)f2bf(b) << 16);
}
// async global->LDS, 16B per lane; lds base must be wave-uniform
__device__ __forceinline__ void gl16(const void* g, void* l) {
    __builtin_amdgcn_global_load_lds(
        (const __attribute__((address_space(1))) unsigned int*)g,
        (__attribute__((address_space(3))) unsigned int*)l, 16, 0, 0);
}

// ---------------- merged: mask downsample + Wq/Wo bf16 convert ----------------
__global__ void k_mdcvt(const float* __restrict__ mask, float* __restrict__ md,
                        const float* __restrict__ wq, const float* __restrict__ wo,
                        ushort_t* __restrict__ wqb, ushort_t* __restrict__ wob) {
    int bid = blockIdx.x;
    if (bid < 2048) {
        int i = bid * 256 + threadIdx.x;       // [0, 524288)
        if (i < 262144) wqb[i] = f2bf(wq[i]);
        else            wob[i - 262144] = f2bf(wo[i - 262144]);
    } else {
        int b = bid - 2048;                    // 2 blocks
        int l = threadIdx.x;
        int hr = l >> 4, wr = l & 15;
        const float* mp = mask + (size_t)b * NPIX;
        float s = 0.f;
#pragma unroll
        for (int i = 0; i < 8; ++i)
#pragma unroll
            for (int j = 0; j < 8; ++j)
                s += mp[(hr * 8 + i) * WIMG + wr * 8 + j];
        md[b * LTOK + l] = s * (1.f / 64.f);
    }
}

// ---------------- x [b][c][n] f32 -> xt [b][n][c] bf16, vectorized stores ------
__global__ __launch_bounds__(256) void k_xt(const float* __restrict__ x, ushort_t* __restrict__ xt) {
    __shared__ float t[64][65];
    int b = blockIdx.z, c0 = blockIdx.y * 64, n0 = blockIdx.x * 64;
    int tn = threadIdx.x & 63, tc = threadIdx.x >> 6;
    const float* xb = x + ((size_t)b * DIMC + c0) * NPIX + n0;
#pragma unroll
    for (int p = 0; p < 16; ++p)
        t[tc + p * 4][tn] = xb[(size_t)(tc + p * 4) * NPIX + tn];
    __syncthreads();
    ushort_t* xtb = xt + ((size_t)b * NPIX + n0) * DIMC + c0;
    int tc4 = threadIdx.x & 15, ng = threadIdx.x >> 4;
#pragma unroll
    for (int p = 0; p < 4; ++p) {
        int nl = ng + p * 16;
        ushort4 v;
        v.x = f2bf(t[4 * tc4 + 0][nl]);
        v.y = f2bf(t[4 * tc4 + 1][nl]);
        v.z = f2bf(t[4 * tc4 + 2][nl]);
        v.w = f2bf(t[4 * tc4 + 3][nl]);
        *(ushort4*)&xtb[(size_t)nl * DIMC + 4 * tc4] = v;
    }
}

// ---------------- Wkv [o][c][ij] f32 -> Wkvp [o][ij*512+c] bf16, vec stores ----
__global__ __launch_bounds__(256) void k_wkvp(const float* __restrict__ Wkv, ushort_t* __restrict__ Wp) {
    __shared__ float t[64][65];
    int o = blockIdx.y, c0 = blockIdx.x * 64;
    int tij = threadIdx.x & 63, tc = threadIdx.x >> 6;
    const float* wb = Wkv + ((size_t)o * DIMC + c0) * 64;
#pragma unroll
    for (int p = 0; p < 16; ++p)
        t[tc + p * 4][tij] = wb[(size_t)(tc + p * 4) * 64 + tij];
    __syncthreads();
    ushort_t* wpb = Wp + (size_t)o * KVK + c0;
    int tj4 = threadIdx.x & 15, ig = threadIdx.x >> 4;
#pragma unroll
    for (int p = 0; p < 4; ++p) {
        int ij = ig + p * 16;
        ushort4 v;
        v.x = f2bf(t[4 * tj4 + 0][ij]);
        v.y = f2bf(t[4 * tj4 + 1][ij]);
        v.z = f2bf(t[4 * tj4 + 2][ij]);
        v.w = f2bf(t[4 * tj4 + 3][ij]);
        *(ushort4*)&wpb[(size_t)ij * DIMC + 4 * tj4] = v;
    }
}

// ================= MFMA GEMM (1x1 convs), 128x128 tile, BK=64, dbuf prefetch =================
// T2 swizzle, pre-swizzled-source form: LDS dest linear, global k-block XORed
// with (row&7) at stage, fragment read XORs the slot index the same way.
template<int EPI>
__global__ __launch_bounds__(256) void k_gemm_qo(
    const ushort_t* __restrict__ A, long sA,
    const ushort_t* __restrict__ B, long sB,
    void* __restrict__ Yv) {
    __shared__ ushort_t Asm[2][128 * 64];
    __shared__ ushort_t Bsm[2][128 * 64];
    const int tid = threadIdx.x;
    const int w = tid >> 6, lane = tid & 63;
    const int wm = w >> 1, wn = w & 1;
    const int lr = lane & 15, lg = lane >> 4;
    const int bz = blockIdx.z;
    const int m0 = blockIdx.y * 128, c0 = blockIdx.x * 128;
    const ushort_t* Ab = A + (size_t)bz * sA;
    const ushort_t* Bb = B + (size_t)bz * sB;

    f32x4 acc[4][4];
    const f32x4 zz = {0.f, 0.f, 0.f, 0.f};
#pragma unroll
    for (int i = 0; i < 4; ++i)
#pragma unroll
        for (int j = 0; j < 4; ++j) acc[i][j] = zz;

#define STAGE_QO(buf, k0) do {                                               \
    _Pragma("unroll")                                                        \
    for (int r = 0; r < 4; ++r) {                                            \
        int slot = r * 256 + tid;                                            \
        int m = slot >> 3, kb = slot & 7;                                    \
        int kbs = kb ^ (m & 7);                                              \
        gl16(Ab + (size_t)(m0 + m) * DIMC + (k0) + kbs * 8,                  \
             &Asm[buf][(size_t)(r * 256 + w * 64) * 8]);                     \
    }                                                                        \
    _Pragma("unroll")                                                        \
    for (int r = 0; r < 4; ++r) {                                            \
        int slot = r * 256 + tid;                                            \
        int m = slot >> 3, kb = slot & 7;                                    \
        int kbs = kb ^ (m & 7);                                              \
        gl16(Bb + (size_t)(c0 + m) * DIMC + (k0) + kbs * 8,                  \
             &Bsm[buf][(size_t)(r * 256 + w * 64) * 8]);                     \
    }                                                                        \
} while (0)

    STAGE_QO(0, 0);
    __syncthreads();
    int cur = 0;
#pragma unroll 1
    for (int t = 0; t < 8; ++t) {
        if (t < 7) STAGE_QO(cur ^ 1, (t + 1) * 64);
#pragma unroll
        for (int kk = 0; kk < 2; ++kk) {
            bf16x8 af[4], bfr[4];
#pragma unroll
            for (int i = 0; i < 4; ++i) {
                int row = wm * 64 + i * 16 + lr;
                af[i] = *(const bf16x8*)&Asm[cur][(size_t)(row * 8 + ((kk * 4 + lg) ^ (row & 7))) * 8];
            }
#pragma unroll
            for (int j = 0; j < 4; ++j) {
                int row = wn * 64 + j * 16 + lr;
                bfr[j] = *(const bf16x8*)&Bsm[cur][(size_t)(row * 8 + ((kk * 4 + lg) ^ (row & 7))) * 8];
            }
#pragma unroll
            for (int i = 0; i < 4; ++i)
#pragma unroll
                for (int j = 0; j < 4; ++j)
                    acc[i][j] = __builtin_amdgcn_mfma_f32_16x16x32_bf16(af[i], bfr[j], acc[i][j], 0, 0, 0);
        }
        if (t < 7) {
            __syncthreads();   // drains vmcnt(0): prefetch flew during the MFMAs above
            cur ^= 1;
        }
    }
#undef STAGE_QO

    if (EPI == 0) {
        ushort_t* q = (ushort_t*)Yv + (size_t)bz * ((size_t)NPIX * DIMC);
#pragma unroll
        for (int i = 0; i < 4; ++i) {
            int d0 = m0 + wm * 64 + i * 16 + lg * 4;
#pragma unroll
            for (int j = 0; j < 4; ++j) {
                int n = c0 + wn * 64 + j * 16 + lr;
                ushort4 v;
                v.x = f2bf(acc[i][j][0]); v.y = f2bf(acc[i][j][1]);
                v.z = f2bf(acc[i][j][2]); v.w = f2bf(acc[i][j][3]);
                *(ushort4*)&q[(size_t)n * DIMC + d0] = v;
            }
        }
    } else {
        float* O = (float*)Yv + (size_t)bz * ((size_t)DIMC * NPIX);
#pragma unroll
        for (int i = 0; i < 4; ++i) {
            int n0r = m0 + wm * 64 + i * 16 + lg * 4;
#pragma unroll
            for (int j = 0; j < 4; ++j) {
                int o = c0 + wn * 64 + j * 16 + lr;
                *(f32x4*)&O[(size_t)o * NPIX + n0r] = acc[i][j];
            }
        }
    }
}

// ================= MFMA kv conv (im2col GEMM), split-K=16, dbuf prefetch =================
// R6-proven version: 3-D grid, gl16 from xt/wkvp, T2 pre-swizzled source.
__global__ __launch_bounds__(256) void k_convkv_mfma(
    const ushort_t* __restrict__ xt, const ushort_t* __restrict__ Wp,
    float* __restrict__ part) {
    __shared__ ushort_t Asm[2][128 * 64];
    __shared__ ushort_t Bsm[2][128 * 64];
    const int tid = threadIdx.x;
    const int w = tid >> 6, lane = tid & 63;
    const int wm = w >> 1, wn = w & 1;
    const int lr = lane & 15, lg = lane >> 4;
    const int z = blockIdx.z;
    const int b = z >> 4, ks = z & 15;
    const int m0 = blockIdx.y * 128, n0 = blockIdx.x * 128;
    const ushort_t* xtb = xt + (size_t)b * NPIX * DIMC;
    const int kbeg = ks * KCHUNK;

    f32x4 acc[4][4];
    const f32x4 zz = {0.f, 0.f, 0.f, 0.f};
#pragma unroll
    for (int i = 0; i < 4; ++i)
#pragma unroll
        for (int j = 0; j < 4; ++j) acc[i][j] = zz;

#define STAGE_KV(buf, k0) do {                                               \
    _Pragma("unroll")                                                        \
    for (int r = 0; r < 4; ++r) {                                            \
        int slot = r * 256 + tid;                                            \
        int m = slot >> 3, kb = slot & 7;                                    \
        int kbs = kb ^ (m & 7);                                              \
        gl16(Wp + (size_t)(m0 + m) * KVK + (k0) + kbs * 8,                   \
             &Asm[buf][(size_t)(r * 256 + w * 64) * 8]);                     \
    }                                                                        \
    _Pragma("unroll")                                                        \
    for (int r = 0; r < 4; ++r) {                                            \
        int slot = r * 256 + tid;                                            \
        int nn = slot >> 3, kb = slot & 7;                                   \
        int l = n0 + nn, hr = l >> 4, wr = l & 15;                           \
        int kp = (k0) + (kb ^ (nn & 7)) * 8;                                 \
        int ij = kp >> 9, ck = kp & 511;                                     \
        int ii = ij >> 3, jj = ij & 7;                                       \
        gl16(xtb + (size_t)((hr * 8 + ii) * WIMG + wr * 8 + jj) * DIMC + ck, \
             &Bsm[buf][(size_t)(r * 256 + w * 64) * 8]);                     \
    }                                                                        \
} while (0)

    STAGE_KV(0, kbeg);
    __syncthreads();
    int cur = 0;
#pragma unroll 1
    for (int t = 0; t < KCHUNK / 64; ++t) {
        if (t < KCHUNK / 64 - 1) STAGE_KV(cur ^ 1, kbeg + (t + 1) * 64);
#pragma unroll
        for (int kk = 0; kk < 2; ++kk) {
            bf16x8 af[4], bfr[4];
#pragma unroll
            for (int i = 0; i < 4; ++i) {
                int row = wm * 64 + i * 16 + lr;
                af[i] = *(const bf16x8*)&Asm[cur][(size_t)(row * 8 + ((kk * 4 + lg) ^ (row & 7))) * 8];
            }
#pragma unroll
            for (int j = 0; j < 4; ++j) {
                int row = wn * 64 + j * 16 + lr;
                bfr[j] = *(const bf16x8*)&Bsm[cur][(size_t)(row * 8 + ((kk * 4 + lg) ^ (row & 7))) * 8];
            }
#pragma unroll
            for (int i = 0; i < 4; ++i)
#pragma unroll
                for (int j = 0; j < 4; ++j)
                    acc[i][j] = __builtin_amdgcn_mfma_f32_16x16x32_bf16(af[i], bfr[j], acc[i][j], 0, 0, 0);
        }
        if (t < KCHUNK / 64 - 1) {
            __syncthreads();
            cur ^= 1;
        }
    }
#undef STAGE_KV

    float* P = part + (size_t)z * (LTOK * 1024);
#pragma unroll
    for (int i = 0; i < 4; ++i) {
        int o0 = m0 + wm * 64 + i * 16 + lg * 4;
#pragma unroll
        for (int j = 0; j < 4; ++j) {
            int l = n0 + wn * 64 + j * 16 + lr;
            *(f32x4*)&P[(size_t)l * 1024 + o0] = acc[i][j];
        }
    }
}

// reduce partials -> kt bf16 [b][h][l][64], vt bf16 [b][h][d][256]
__global__ void k_kvreduce(const float* __restrict__ part,
                           ushort_t* __restrict__ kt, ushort_t* __restrict__ vt) {
    int idx = blockIdx.x * 256 + threadIdx.x;   // [0, 2*256*1024)
    int o = idx & 1023;
    int rest = idx >> 10;
    int l = rest & 255, b = rest >> 8;
    float s = 0.f;
#pragma unroll
    for (int ks = 0; ks < SPLITK; ++ks)
        s += part[(size_t)(b * SPLITK + ks) * (LTOK * 1024) + (size_t)l * 1024 + o];
    int h = (o >> 6) & 7, d = o & 63;
    if (o < 512)
        kt[(((size_t)b * 8 + h) * 256 + l) * 64 + d] = f2bf(s);
    else
        vt[(((size_t)b * 8 + h) * 64 + d) * 256 + l] = f2bf(s);
}

// ================= MFMA fused attention (R6 proven version) =================
__global__ __launch_bounds__(256, 2) void k_attn_mfma(
    const ushort_t* __restrict__ qbf, const ushort_t* __restrict__ kt,
    const ushort_t* __restrict__ vt, const float* __restrict__ mask,
    const float* __restrict__ md, ushort_t* __restrict__ obuf) {
    __shared__ ushort_t Qs[128 * 64];   // 16KB, rows 128B, 8 slots of 16B, XOR-swizzled
    __shared__ ushort_t Ks[256 * 64];   // 32KB
    __shared__ ushort_t Vs[64 * 256];   // 32KB, rows 512B, 32 slots

    const int tid = threadIdx.x;
    const int w = tid >> 6, lane = tid & 63;
    const int g = lane >> 4, ln = lane & 15;
    const int bh = blockIdx.y, b = bh >> 3, h = bh & 7;
    const int bb = bh & 1;              // bias batch quirk: (b*8+h) % 2
    const int n0 = blockIdx.x * 128;

    {
        const ushort_t* src = qbf + ((size_t)b * NPIX + n0) * DIMC + h * 64;
#pragma unroll
        for (int p = 0; p < 4; ++p) {
            int id = p * 256 + tid;
            int r = id >> 3, s = id & 7;
            uint4 v = *(const uint4*)(src + (size_t)r * DIMC + s * 8);
            *(uint4*)&Qs[(r * 8 + (s ^ (r & 7))) * 8] = v;
        }
    }
    {
        const ushort_t* src = kt + (size_t)bh * 256 * 64;
#pragma unroll
        for (int p = 0; p < 8; ++p) {
            int id = p * 256 + tid;
            int r = id >> 3, s = id & 7;
            uint4 v = *(const uint4*)(src + r * 64 + s * 8);
            *(uint4*)&Ks[(r * 8 + (s ^ (r & 7))) * 8] = v;
        }
    }
    {
        const ushort_t* src = vt + (size_t)bh * 64 * 256;
#pragma unroll
        for (int p = 0; p < 8; ++p) {
            int id = p * 256 + tid;
            int r = id >> 5, s = id & 31;
            uint4 v = *(const uint4*)(src + r * 256 + s * 8);
            *(uint4*)&Vs[(r * 32 + (s ^ (r & 7))) * 8] = v;
        }
    }
    __syncthreads();

    f32x4 acc[2][16];
    const f32x4 zz = {0.f, 0.f, 0.f, 0.f};
#pragma unroll
    for (int nf = 0; nf < 2; ++nf)
#pragma unroll
        for (int f = 0; f < 16; ++f) acc[nf][f] = zz;

    bf16x8 qf[2][2];
#pragma unroll
    for (int nf = 0; nf < 2; ++nf)
#pragma unroll
        for (int kk = 0; kk < 2; ++kk) {
            int nl = 32 * w + nf * 16 + ln;
            qf[nf][kk] = *(const bf16x8*)&Qs[(nl * 8 + ((kk * 4 + g) ^ (nl & 7))) * 8];
        }
#pragma unroll
    for (int f = 0; f < 16; ++f) {
#pragma unroll
        for (int kk = 0; kk < 2; ++kk) {
            int l = f * 16 + ln;
            bf16x8 kf = *(const bf16x8*)&Ks[(l * 8 + ((kk * 4 + g) ^ (l & 7))) * 8];
            acc[0][f] = __builtin_amdgcn_mfma_f32_16x16x32_bf16(kf, qf[0][kk], acc[0][f], 0, 0, 0);
            acc[1][f] = __builtin_amdgcn_mfma_f32_16x16x32_bf16(kf, qf[1][kk], acc[1][f], 0, 0, 0);
        }
    }

    float inv[2];
    uint2 pb[2][16];
#pragma unroll
    for (int nf = 0; nf < 2; ++nf) {
        float mval = mask[(size_t)bb * NPIX + n0 + 32 * w + nf * 16 + ln];
        float mx = -1e30f;
#pragma unroll
        for (int f = 0; f < 16; ++f) {
            float4 md4 = *(const float4*)&md[bb * LTOK + f * 16 + g * 4];
            float s0 = (acc[nf][f][0] + __logf(mval * md4.x + EPSB)) * SCALEF;
            float s1 = (acc[nf][f][1] + __logf(mval * md4.y + EPSB)) * SCALEF;
            float s2 = (acc[nf][f][2] + __logf(mval * md4.z + EPSB)) * SCALEF;
            float s3 = (acc[nf][f][3] + __logf(mval * md4.w + EPSB)) * SCALEF;
            acc[nf][f][0] = s0; acc[nf][f][1] = s1;
            acc[nf][f][2] = s2; acc[nf][f][3] = s3;
            mx = fmaxf(mx, fmaxf(fmaxf(s0, s1), fmaxf(s2, s3)));
        }
        mx = fmaxf(mx, __shfl_xor(mx, 16));
        mx = fmaxf(mx, __shfl_xor(mx, 32));
        float sum = 0.f;
#pragma unroll
        for (int f = 0; f < 16; ++f) {
            float p0 = __expf(acc[nf][f][0] - mx);
            float p1 = __expf(acc[nf][f][1] - mx);
            float p2 = __expf(acc[nf][f][2] - mx);
            float p3 = __expf(acc[nf][f][3] - mx);
            sum += (p0 + p1) + (p2 + p3);
            pb[nf][f].x = pk2bf(p0, p1);
            pb[nf][f].y = pk2bf(p2, p3);
        }
        sum += __shfl_xor(sum, 16);
        sum += __shfl_xor(sum, 32);
        inv[nf] = 1.f / sum;
    }

    f32x4 acc2[2][4];
#pragma unroll
    for (int nf = 0; nf < 2; ++nf)
#pragma unroll
        for (int df = 0; df < 4; ++df) acc2[nf][df] = zz;

    const int srcLo = ((g & 1) << 5) + ln;
    const bool selHi = (g >> 1);
#pragma unroll
    for (int ks = 0; ks < 8; ++ks) {
        bf16x8 vf[4];
#pragma unroll
        for (int df = 0; df < 4; ++df) {
            int d = df * 16 + ln;
            vf[df] = *(const bf16x8*)&Vs[(d * 32 + ((ks * 4 + g) ^ (d & 7))) * 8];
        }
#pragma unroll
        for (int nf = 0; nf < 2; ++nf) {
            uint_t e0 = pb[nf][2 * ks].x,     e1 = pb[nf][2 * ks].y;
            uint_t o0 = pb[nf][2 * ks + 1].x, o1 = pb[nf][2 * ks + 1].y;
            uint_t lo0 = __shfl((int)e0, srcLo), lo1 = __shfl((int)e1, srcLo);
            uint_t lo0b = __shfl((int)o0, srcLo), lo1b = __shfl((int)o1, srcLo);
            uint_t hi0 = __shfl((int)e0, srcLo + 16), hi1 = __shfl((int)e1, srcLo + 16);
            uint_t hi0b = __shfl((int)o0, srcLo + 16), hi1b = __shfl((int)o1, srcLo + 16);
            union { uint_t u[4]; bf16x8 v; } bfr;
            bfr.u[0] = selHi ? lo0b : lo0;
            bfr.u[1] = selHi ? lo1b : lo1;
            bfr.u[2] = selHi ? hi0b : hi0;
            bfr.u[3] = selHi ? hi1b : hi1;
#pragma unroll
            for (int df = 0; df < 4; ++df)
                acc2[nf][df] = __builtin_amdgcn_mfma_f32_16x16x32_bf16(vf[df], bfr.v, acc2[nf][df], 0, 0, 0);
        }
    }

#pragma unroll
    for (int nf = 0; nf < 2; ++nf) {
        int n = n0 + 32 * w + nf * 16 + ln;
        ushort_t* op = obuf + ((size_t)b * NPIX + n) * DIMC + h * 64;
#pragma unroll
        for (int df = 0; df < 4; ++df) {
            ushort4 v;
            v.x = f2bf(acc2[nf][df][0] * inv[nf]);
            v.y = f2bf(acc2[nf][df][1] * inv[nf]);
            v.z = f2bf(acc2[nf][df][2] * inv[nf]);
            v.w = f2bf(acc2[nf][df][3] * inv[nf]);
            *(ushort4*)&op[df * 16 + g * 4] = v;
        }
    }
}

extern "C" void kernel_launch(void* const* d_in, const int* in_sizes, int n_in,
                              void* d_out, int out_size, void* d_ws, size_t ws_size,
                              hipStream_t stream) {
    const float* x    = (const float*)d_in[0];
    const float* mask = (const float*)d_in[1];
    const float* Wq   = (const float*)d_in[2];
    const float* Wkv  = (const float*)d_in[3];
    const float* Wo   = (const float*)d_in[4];
    float* out = (float*)d_out;

    char* ws = (char*)d_ws;
    float*    md   = (float*)(ws);                         // 4 KB
    ushort_t* xt   = (ushort_t*)(ws + 4096);               // 33.55 MB
    ushort_t* wkvp = (ushort_t*)(ws + 33558528);           // 67.1 MB
    ushort_t* qbf  = wkvp;                                 // alias: written after convkv
    ushort_t* ktb  = (ushort_t*)(ws + 100667392);          // 0.5 MB
    ushort_t* vtb  = ktb + 524288;                         // 0.5 MB
    ushort_t* wqb  = (ushort_t*)(ws + 102764544);          // 0.5 MB
    ushort_t* wob  = wqb + 262144;                         // 0.5 MB
    float*    part = (float*)(ws + 103813120);             // 33.55 MB
    ushort_t* aob  = (ushort_t*)part;                      // alias: written after kvreduce

    k_mdcvt<<<dim3(2050), dim3(256), 0, stream>>>(mask, md, Wq, Wo, wqb, wob);
    k_xt<<<dim3(NPIX / 64, DIMC / 64, BATCH), dim3(256), 0, stream>>>(x, xt);
    k_wkvp<<<dim3(DIMC / 64, 1024), dim3(256), 0, stream>>>(Wkv, wkvp);

    k_convkv_mfma<<<dim3(LTOK / 128, 1024 / 128, BATCH * SPLITK), dim3(256), 0, stream>>>(xt, wkvp, part);
    k_kvreduce<<<dim3(2048), dim3(256), 0, stream>>>(part, ktb, vtb);

    k_gemm_qo<0><<<dim3(NPIX / 128, DIMC / 128, BATCH), dim3(256), 0, stream>>>(
        wqb, 0L, xt, (long)NPIX * DIMC, qbf);

    k_attn_mfma<<<dim3(NPIX / 128, BATCH * HEADS), dim3(256), 0, stream>>>(
        qbf, ktb, vtb, mask, md, aob);

    k_gemm_qo<1><<<dim3(DIMC / 128, NPIX / 128, BATCH), dim3(256), 0, stream>>>(
        aob, (long)NPIX * DIMC, wob, 0L, out);
}

// Round 11
// 243.534 us; speedup vs baseline: 1.1033x; 1.0178x over previous
//
#include <hip/hip_runtime.h>
#include <math.h>

#define DIMC  512
#define HEADS 8
#define HD    64
#define NPIX  16384   // 128*128
#define LTOK  256     // 16*16
#define BATCH 2
#define WIMG  128
#define KVK   32768   // 512*8*8
#define EPSB  1e-8f
#define SCALEF 0.125f // 64^-0.5
#define SPLITK 16
#define KCHUNK (KVK / SPLITK)   // 2048

typedef unsigned short ushort_t;
typedef unsigned int uint_t;
using bf16x8 = __attribute__((ext_vector_type(8))) __bf16;
using f32x4  = __attribute__((ext_vector_type(4))) float;

__device__ __forceinline__ ushort_t f2bf(float f) {
    union { float f; unsigned u; } v; v.f = f;
    unsigned r = v.u + 0x7FFFu + ((v.u >> 16) & 1u);
    return (ushort_t)(r >> 16);
}
__device__ __forceinline__ uint_t pk2bf(float a, float b) {
    return (uint_t)f2bf(a) | ((uint_t)f2bf(b) << 16);
}
// async global->LDS, 16B per lane; lds base must be wave-uniform
__device__ __forceinline__ void gl16(const void* g, void* l) {
    __builtin_amdgcn_global_load_lds(
        (const __attribute__((address_space(1))) unsigned int*)g,
        (__attribute__((address_space(3))) unsigned int*)l, 16, 0, 0);
}

// ================= merged prep: xt transpose + Wkv permute + cvt + maskdown =================
// grid 14338 x 256, block-uniform branches:
//   [0,4096)      x [b][c][n] f32 -> xt [b][n][c] bf16 (LDS transpose, vec stores)
//   [4096,12288)  Wkv [o][c][ij] -> Wkvp [o][ij*512+c] bf16
//   [12288,14336) Wq/Wo f32 -> bf16
//   [14336,14338) mask avg-pool 8x8 -> md
__global__ __launch_bounds__(256) void k_prep(
    const float* __restrict__ x, ushort_t* __restrict__ xt,
    const float* __restrict__ Wkv, ushort_t* __restrict__ Wp,
    const float* __restrict__ mask, float* __restrict__ md,
    const float* __restrict__ wq, const float* __restrict__ wo,
    ushort_t* __restrict__ wqb, ushort_t* __restrict__ wob) {
    __shared__ float t[64][65];
    const int bid = blockIdx.x;
    if (bid < 4096) {
        int b = bid >> 11, c0 = ((bid >> 8) & 7) * 64, n0 = (bid & 255) * 64;
        int tn = threadIdx.x & 63, tc = threadIdx.x >> 6;
        const float* xb = x + ((size_t)b * DIMC + c0) * NPIX + n0;
#pragma unroll
        for (int p = 0; p < 16; ++p)
            t[tc + p * 4][tn] = xb[(size_t)(tc + p * 4) * NPIX + tn];
        __syncthreads();
        ushort_t* xtb = xt + ((size_t)b * NPIX + n0) * DIMC + c0;
        int tc4 = threadIdx.x & 15, ng = threadIdx.x >> 4;
#pragma unroll
        for (int p = 0; p < 4; ++p) {
            int nl = ng + p * 16;
            ushort4 v;
            v.x = f2bf(t[4 * tc4 + 0][nl]);
            v.y = f2bf(t[4 * tc4 + 1][nl]);
            v.z = f2bf(t[4 * tc4 + 2][nl]);
            v.w = f2bf(t[4 * tc4 + 3][nl]);
            *(ushort4*)&xtb[(size_t)nl * DIMC + 4 * tc4] = v;
        }
    } else if (bid < 12288) {
        int tb = bid - 4096;
        int o = tb >> 3, c0 = (tb & 7) * 64;
        int tij = threadIdx.x & 63, tc = threadIdx.x >> 6;
        const float* wb = Wkv + ((size_t)o * DIMC + c0) * 64;
#pragma unroll
        for (int p = 0; p < 16; ++p)
            t[tc + p * 4][tij] = wb[(size_t)(tc + p * 4) * 64 + tij];
        __syncthreads();
        ushort_t* wpb = Wp + (size_t)o * KVK + c0;
        int tj4 = threadIdx.x & 15, ig = threadIdx.x >> 4;
#pragma unroll
        for (int p = 0; p < 4; ++p) {
            int ij = ig + p * 16;
            ushort4 v;
            v.x = f2bf(t[4 * tj4 + 0][ij]);
            v.y = f2bf(t[4 * tj4 + 1][ij]);
            v.z = f2bf(t[4 * tj4 + 2][ij]);
            v.w = f2bf(t[4 * tj4 + 3][ij]);
            *(ushort4*)&wpb[(size_t)ij * DIMC + 4 * tj4] = v;
        }
    } else if (bid < 14336) {
        int i = (bid - 12288) * 256 + threadIdx.x;     // [0, 524288)
        if (i < 262144) wqb[i] = f2bf(wq[i]);
        else            wob[i - 262144] = f2bf(wo[i - 262144]);
    } else {
        int b = bid - 14336;
        int l = threadIdx.x;
        int hr = l >> 4, wr = l & 15;
        const float* mp = mask + (size_t)b * NPIX;
        float s = 0.f;
#pragma unroll
        for (int i = 0; i < 8; ++i)
#pragma unroll
            for (int j = 0; j < 8; ++j)
                s += mp[(hr * 8 + i) * WIMG + wr * 8 + j];
        md[b * LTOK + l] = s * (1.f / 64.f);
    }
}

// ================= MFMA kv conv (im2col GEMM), split-K=16, dbuf prefetch =================
// R6-proven: 3-D grid, gl16 from xt/wkvp, T2 pre-swizzled source.
__global__ __launch_bounds__(256) void k_convkv_mfma(
    const ushort_t* __restrict__ xt, const ushort_t* __restrict__ Wp,
    float* __restrict__ part) {
    __shared__ ushort_t Asm[2][128 * 64];
    __shared__ ushort_t Bsm[2][128 * 64];
    const int tid = threadIdx.x;
    const int w = tid >> 6, lane = tid & 63;
    const int wm = w >> 1, wn = w & 1;
    const int lr = lane & 15, lg = lane >> 4;
    const int z = blockIdx.z;
    const int b = z >> 4, ks = z & 15;
    const int m0 = blockIdx.y * 128, n0 = blockIdx.x * 128;
    const ushort_t* xtb = xt + (size_t)b * NPIX * DIMC;
    const int kbeg = ks * KCHUNK;

    f32x4 acc[4][4];
    const f32x4 zz = {0.f, 0.f, 0.f, 0.f};
#pragma unroll
    for (int i = 0; i < 4; ++i)
#pragma unroll
        for (int j = 0; j < 4; ++j) acc[i][j] = zz;

#define STAGE_KV(buf, k0) do {                                               \
    _Pragma("unroll")                                                        \
    for (int r = 0; r < 4; ++r) {                                            \
        int slot = r * 256 + tid;                                            \
        int m = slot >> 3, kb = slot & 7;                                    \
        int kbs = kb ^ (m & 7);                                              \
        gl16(Wp + (size_t)(m0 + m) * KVK + (k0) + kbs * 8,                   \
             &Asm[buf][(size_t)(r * 256 + w * 64) * 8]);                     \
    }                                                                        \
    _Pragma("unroll")                                                        \
    for (int r = 0; r < 4; ++r) {                                            \
        int slot = r * 256 + tid;                                            \
        int nn = slot >> 3, kb = slot & 7;                                   \
        int l = n0 + nn, hr = l >> 4, wr = l & 15;                           \
        int kp = (k0) + (kb ^ (nn & 7)) * 8;                                 \
        int ij = kp >> 9, ck = kp & 511;                                     \
        int ii = ij >> 3, jj = ij & 7;                                       \
        gl16(xtb + (size_t)((hr * 8 + ii) * WIMG + wr * 8 + jj) * DIMC + ck, \
             &Bsm[buf][(size_t)(r * 256 + w * 64) * 8]);                     \
    }                                                                        \
} while (0)

    STAGE_KV(0, kbeg);
    __syncthreads();
    int cur = 0;
#pragma unroll 1
    for (int t = 0; t < KCHUNK / 64; ++t) {
        if (t < KCHUNK / 64 - 1) STAGE_KV(cur ^ 1, kbeg + (t + 1) * 64);
#pragma unroll
        for (int kk = 0; kk < 2; ++kk) {
            bf16x8 af[4], bfr[4];
#pragma unroll
            for (int i = 0; i < 4; ++i) {
                int row = wm * 64 + i * 16 + lr;
                af[i] = *(const bf16x8*)&Asm[cur][(size_t)(row * 8 + ((kk * 4 + lg) ^ (row & 7))) * 8];
            }
#pragma unroll
            for (int j = 0; j < 4; ++j) {
                int row = wn * 64 + j * 16 + lr;
                bfr[j] = *(const bf16x8*)&Bsm[cur][(size_t)(row * 8 + ((kk * 4 + lg) ^ (row & 7))) * 8];
            }
#pragma unroll
            for (int i = 0; i < 4; ++i)
#pragma unroll
                for (int j = 0; j < 4; ++j)
                    acc[i][j] = __builtin_amdgcn_mfma_f32_16x16x32_bf16(af[i], bfr[j], acc[i][j], 0, 0, 0);
        }
        if (t < KCHUNK / 64 - 1) {
            __syncthreads();
            cur ^= 1;
        }
    }
#undef STAGE_KV

    float* P = part + (size_t)z * (LTOK * 1024);
#pragma unroll
    for (int i = 0; i < 4; ++i) {
        int o0 = m0 + wm * 64 + i * 16 + lg * 4;
#pragma unroll
        for (int j = 0; j < 4; ++j) {
            int l = n0 + wn * 64 + j * 16 + lr;
            *(f32x4*)&P[(size_t)l * 1024 + o0] = acc[i][j];
        }
    }
}

// ================= merged: q-projection GEMM + kv reduce =================
// grid 3072 x 256: [0,1024) gemm<0> blocks (long pole, dispatched first),
// [1024,3072) kvreduce blocks (tail-packing BW work).
__global__ __launch_bounds__(256) void k_g0red(
    const ushort_t* __restrict__ wqb, const ushort_t* __restrict__ xt,
    ushort_t* __restrict__ qbf,
    const float* __restrict__ part,
    ushort_t* __restrict__ kt, ushort_t* __restrict__ vt) {
    __shared__ ushort_t Asm[2][128 * 64];
    __shared__ ushort_t Bsm[2][128 * 64];
    const int bid = blockIdx.x;
    if (bid < 1024) {
        const int tid = threadIdx.x;
        const int w = tid >> 6, lane = tid & 63;
        const int wm = w >> 1, wn = w & 1;
        const int lr = lane & 15, lg = lane >> 4;
        const int c0 = (bid & 127) * 128;          // over NPIX
        const int m0 = ((bid >> 7) & 3) * 128;     // over DIMC (Wq rows)
        const int bz = bid >> 9;
        const ushort_t* Ab = wqb;
        const ushort_t* Bb = xt + (size_t)bz * NPIX * DIMC;

        f32x4 acc[4][4];
        const f32x4 zz = {0.f, 0.f, 0.f, 0.f};
#pragma unroll
        for (int i = 0; i < 4; ++i)
#pragma unroll
            for (int j = 0; j < 4; ++j) acc[i][j] = zz;

#define STAGE_G0(buf, k0) do {                                               \
    _Pragma("unroll")                                                        \
    for (int r = 0; r < 4; ++r) {                                            \
        int slot = r * 256 + tid;                                            \
        int m = slot >> 3, kb = slot & 7;                                    \
        int kbs = kb ^ (m & 7);                                              \
        gl16(Ab + (size_t)(m0 + m) * DIMC + (k0) + kbs * 8,                  \
             &Asm[buf][(size_t)(r * 256 + w * 64) * 8]);                     \
    }                                                                        \
    _Pragma("unroll")                                                        \
    for (int r = 0; r < 4; ++r) {                                            \
        int slot = r * 256 + tid;                                            \
        int m = slot >> 3, kb = slot & 7;                                    \
        int kbs = kb ^ (m & 7);                                              \
        gl16(Bb + (size_t)(c0 + m) * DIMC + (k0) + kbs * 8,                  \
             &Bsm[buf][(size_t)(r * 256 + w * 64) * 8]);                     \
    }                                                                        \
} while (0)

        STAGE_G0(0, 0);
        __syncthreads();
        int cur = 0;
#pragma unroll 1
        for (int t = 0; t < 8; ++t) {
            if (t < 7) STAGE_G0(cur ^ 1, (t + 1) * 64);
#pragma unroll
            for (int kk = 0; kk < 2; ++kk) {
                bf16x8 af[4], bfr[4];
#pragma unroll
                for (int i = 0; i < 4; ++i) {
                    int row = wm * 64 + i * 16 + lr;
                    af[i] = *(const bf16x8*)&Asm[cur][(size_t)(row * 8 + ((kk * 4 + lg) ^ (row & 7))) * 8];
                }
#pragma unroll
                for (int j = 0; j < 4; ++j) {
                    int row = wn * 64 + j * 16 + lr;
                    bfr[j] = *(const bf16x8*)&Bsm[cur][(size_t)(row * 8 + ((kk * 4 + lg) ^ (row & 7))) * 8];
                }
#pragma unroll
                for (int i = 0; i < 4; ++i)
#pragma unroll
                    for (int j = 0; j < 4; ++j)
                        acc[i][j] = __builtin_amdgcn_mfma_f32_16x16x32_bf16(af[i], bfr[j], acc[i][j], 0, 0, 0);
            }
            if (t < 7) {
                __syncthreads();
                cur ^= 1;
            }
        }
#undef STAGE_G0

        ushort_t* q = qbf + (size_t)bz * ((size_t)NPIX * DIMC);
#pragma unroll
        for (int i = 0; i < 4; ++i) {
            int d0 = m0 + wm * 64 + i * 16 + lg * 4;
#pragma unroll
            for (int j = 0; j < 4; ++j) {
                int n = c0 + wn * 64 + j * 16 + lr;
                ushort4 v;
                v.x = f2bf(acc[i][j][0]); v.y = f2bf(acc[i][j][1]);
                v.z = f2bf(acc[i][j][2]); v.w = f2bf(acc[i][j][3]);
                *(ushort4*)&q[(size_t)n * DIMC + d0] = v;
            }
        }
    } else {
        int idx = (bid - 1024) * 256 + threadIdx.x;   // [0, 2*256*1024)
        int o = idx & 1023;
        int rest = idx >> 10;
        int l = rest & 255, b = rest >> 8;
        float s = 0.f;
#pragma unroll
        for (int ks = 0; ks < SPLITK; ++ks)
            s += part[(size_t)(b * SPLITK + ks) * (LTOK * 1024) + (size_t)l * 1024 + o];
        int h = (o >> 6) & 7, d = o & 63;
        if (o < 512)
            kt[(((size_t)b * 8 + h) * 256 + l) * 64 + d] = f2bf(s);
        else
            vt[(((size_t)b * 8 + h) * 64 + d) * 256 + l] = f2bf(s);
    }
}

// ================= output-projection GEMM (EPI=1 of the old template) =================
__global__ __launch_bounds__(256) void k_gemm_o(
    const ushort_t* __restrict__ A, long sA,
    const ushort_t* __restrict__ B,
    float* __restrict__ Yv) {
    __shared__ ushort_t Asm[2][128 * 64];
    __shared__ ushort_t Bsm[2][128 * 64];
    const int tid = threadIdx.x;
    const int w = tid >> 6, lane = tid & 63;
    const int wm = w >> 1, wn = w & 1;
    const int lr = lane & 15, lg = lane >> 4;
    const int bz = blockIdx.z;
    const int m0 = blockIdx.y * 128, c0 = blockIdx.x * 128;
    const ushort_t* Ab = A + (size_t)bz * sA;
    const ushort_t* Bb = B;

    f32x4 acc[4][4];
    const f32x4 zz = {0.f, 0.f, 0.f, 0.f};
#pragma unroll
    for (int i = 0; i < 4; ++i)
#pragma unroll
        for (int j = 0; j < 4; ++j) acc[i][j] = zz;

#define STAGE_O(buf, k0) do {                                                \
    _Pragma("unroll")                                                        \
    for (int r = 0; r < 4; ++r) {                                            \
        int slot = r * 256 + tid;                                            \
        int m = slot >> 3, kb = slot & 7;                                    \
        int kbs = kb ^ (m & 7);                                              \
        gl16(Ab + (size_t)(m0 + m) * DIMC + (k0) + kbs * 8,                  \
             &Asm[buf][(size_t)(r * 256 + w * 64) * 8]);                     \
    }                                                                        \
    _Pragma("unroll")                                                        \
    for (int r = 0; r < 4; ++r) {                                            \
        int slot = r * 256 + tid;                                            \
        int m = slot >> 3, kb = slot & 7;                                    \
        int kbs = kb ^ (m & 7);                                              \
        gl16(Bb + (size_t)(c0 + m) * DIMC + (k0) + kbs * 8,                  \
             &Bsm[buf][(size_t)(r * 256 + w * 64) * 8]);                     \
    }                                                                        \
} while (0)

    STAGE_O(0, 0);
    __syncthreads();
    int cur = 0;
#pragma unroll 1
    for (int t = 0; t < 8; ++t) {
        if (t < 7) STAGE_O(cur ^ 1, (t + 1) * 64);
#pragma unroll
        for (int kk = 0; kk < 2; ++kk) {
            bf16x8 af[4], bfr[4];
#pragma unroll
            for (int i = 0; i < 4; ++i) {
                int row = wm * 64 + i * 16 + lr;
                af[i] = *(const bf16x8*)&Asm[cur][(size_t)(row * 8 + ((kk * 4 + lg) ^ (row & 7))) * 8];
            }
#pragma unroll
            for (int j = 0; j < 4; ++j) {
                int row = wn * 64 + j * 16 + lr;
                bfr[j] = *(const bf16x8*)&Bsm[cur][(size_t)(row * 8 + ((kk * 4 + lg) ^ (row & 7))) * 8];
            }
#pragma unroll
            for (int i = 0; i < 4; ++i)
#pragma unroll
                for (int j = 0; j < 4; ++j)
                    acc[i][j] = __builtin_amdgcn_mfma_f32_16x16x32_bf16(af[i], bfr[j], acc[i][j], 0, 0, 0);
        }
        if (t < 7) {
            __syncthreads();
            cur ^= 1;
        }
    }
#undef STAGE_O

    float* O = Yv + (size_t)bz * ((size_t)DIMC * NPIX);
#pragma unroll
    for (int i = 0; i < 4; ++i) {
        int n0r = m0 + wm * 64 + i * 16 + lg * 4;
#pragma unroll
        for (int j = 0; j < 4; ++j) {
            int o = c0 + wn * 64 + j * 16 + lr;
            *(f32x4*)&O[(size_t)o * NPIX + n0r] = acc[i][j];
        }
    }
}

// ================= MFMA fused attention (R6 proven version) =================
__global__ __launch_bounds__(256, 2) void k_attn_mfma(
    const ushort_t* __restrict__ qbf, const ushort_t* __restrict__ kt,
    const ushort_t* __restrict__ vt, const float* __restrict__ mask,
    const float* __restrict__ md, ushort_t* __restrict__ obuf) {
    __shared__ ushort_t Qs[128 * 64];   // 16KB, rows 128B, 8 slots of 16B, XOR-swizzled
    __shared__ ushort_t Ks[256 * 64];   // 32KB
    __shared__ ushort_t Vs[64 * 256];   // 32KB, rows 512B, 32 slots

    const int tid = threadIdx.x;
    const int w = tid >> 6, lane = tid & 63;
    const int g = lane >> 4, ln = lane & 15;
    const int bh = blockIdx.y, b = bh >> 3, h = bh & 7;
    const int bb = bh & 1;              // bias batch quirk: (b*8+h) % 2
    const int n0 = blockIdx.x * 128;

    {
        const ushort_t* src = qbf + ((size_t)b * NPIX + n0) * DIMC + h * 64;
#pragma unroll
        for (int p = 0; p < 4; ++p) {
            int id = p * 256 + tid;
            int r = id >> 3, s = id & 7;
            uint4 v = *(const uint4*)(src + (size_t)r * DIMC + s * 8);
            *(uint4*)&Qs[(r * 8 + (s ^ (r & 7))) * 8] = v;
        }
    }
    {
        const ushort_t* src = kt + (size_t)bh * 256 * 64;
#pragma unroll
        for (int p = 0; p < 8; ++p) {
            int id = p * 256 + tid;
            int r = id >> 3, s = id & 7;
            uint4 v = *(const uint4*)(src + r * 64 + s * 8);
            *(uint4*)&Ks[(r * 8 + (s ^ (r & 7))) * 8] = v;
        }
    }
    {
        const ushort_t* src = vt + (size_t)bh * 64 * 256;
#pragma unroll
        for (int p = 0; p < 8; ++p) {
            int id = p * 256 + tid;
            int r = id >> 5, s = id & 31;
            uint4 v = *(const uint4*)(src + r * 256 + s * 8);
            *(uint4*)&Vs[(r * 32 + (s ^ (r & 7))) * 8] = v;
        }
    }
    __syncthreads();

    f32x4 acc[2][16];
    const f32x4 zz = {0.f, 0.f, 0.f, 0.f};
#pragma unroll
    for (int nf = 0; nf < 2; ++nf)
#pragma unroll
        for (int f = 0; f < 16; ++f) acc[nf][f] = zz;

    bf16x8 qf[2][2];
#pragma unroll
    for (int nf = 0; nf < 2; ++nf)
#pragma unroll
        for (int kk = 0; kk < 2; ++kk) {
            int nl = 32 * w + nf * 16 + ln;
            qf[nf][kk] = *(const bf16x8*)&Qs[(nl * 8 + ((kk * 4 + g) ^ (nl & 7))) * 8];
        }
#pragma unroll
    for (int f = 0; f < 16; ++f) {
#pragma unroll
        for (int kk = 0; kk < 2; ++kk) {
            int l = f * 16 + ln;
            bf16x8 kf = *(const bf16x8*)&Ks[(l * 8 + ((kk * 4 + g) ^ (l & 7))) * 8];
            acc[0][f] = __builtin_amdgcn_mfma_f32_16x16x32_bf16(kf, qf[0][kk], acc[0][f], 0, 0, 0);
            acc[1][f] = __builtin_amdgcn_mfma_f32_16x16x32_bf16(kf, qf[1][kk], acc[1][f], 0, 0, 0);
        }
    }

    float inv[2];
    uint2 pb[2][16];
#pragma unroll
    for (int nf = 0; nf < 2; ++nf) {
        float mval = mask[(size_t)bb * NPIX + n0 + 32 * w + nf * 16 + ln];
        float mx = -1e30f;
#pragma unroll
        for (int f = 0; f < 16; ++f) {
            float4 md4 = *(const float4*)&md[bb * LTOK + f * 16 + g * 4];
            float s0 = (acc[nf][f][0] + __logf(mval * md4.x + EPSB)) * SCALEF;
            float s1 = (acc[nf][f][1] + __logf(mval * md4.y + EPSB)) * SCALEF;
            float s2 = (acc[nf][f][2] + __logf(mval * md4.z + EPSB)) * SCALEF;
            float s3 = (acc[nf][f][3] + __logf(mval * md4.w + EPSB)) * SCALEF;
            acc[nf][f][0] = s0; acc[nf][f][1] = s1;
            acc[nf][f][2] = s2; acc[nf][f][3] = s3;
            mx = fmaxf(mx, fmaxf(fmaxf(s0, s1), fmaxf(s2, s3)));
        }
        mx = fmaxf(mx, __shfl_xor(mx, 16));
        mx = fmaxf(mx, __shfl_xor(mx, 32));
        float sum = 0.f;
#pragma unroll
        for (int f = 0; f < 16; ++f) {
            float p0 = __expf(acc[nf][f][0] - mx);
            float p1 = __expf(acc[nf][f][1] - mx);
            float p2 = __expf(acc[nf][f][2] - mx);
            float p3 = __expf(acc[nf][f][3] - mx);
            sum += (p0 + p1) + (p2 + p3);
            pb[nf][f].x = pk2bf(p0, p1);
            pb[nf][f].y = pk2bf(p2, p3);
        }
        sum += __shfl_xor(sum, 16);
        sum += __shfl_xor(sum, 32);
        inv[nf] = 1.f / sum;
    }

    f32x4 acc2[2][4];
#pragma unroll
    for (int nf = 0; nf < 2; ++nf)
#pragma unroll
        for (int df = 0; df < 4; ++df) acc2[nf][df] = zz;

    const int srcLo = ((g & 1) << 5) + ln;
    const bool selHi = (g >> 1);
#pragma unroll
    for (int ks = 0; ks < 8; ++ks) {
        bf16x8 vf[4];
#pragma unroll
        for (int df = 0; df < 4; ++df) {
            int d = df * 16 + ln;
            vf[df] = *(const bf16x8*)&Vs[(d * 32 + ((ks * 4 + g) ^ (d & 7))) * 8];
        }
#pragma unroll
        for (int nf = 0; nf < 2; ++nf) {
            uint_t e0 = pb[nf][2 * ks].x,     e1 = pb[nf][2 * ks].y;
            uint_t o0 = pb[nf][2 * ks + 1].x, o1 = pb[nf][2 * ks + 1].y;
            uint_t lo0 = __shfl((int)e0, srcLo), lo1 = __shfl((int)e1, srcLo);
            uint_t lo0b = __shfl((int)o0, srcLo), lo1b = __shfl((int)o1, srcLo);
            uint_t hi0 = __shfl((int)e0, srcLo + 16), hi1 = __shfl((int)e1, srcLo + 16);
            uint_t hi0b = __shfl((int)o0, srcLo + 16), hi1b = __shfl((int)o1, srcLo + 16);
            union { uint_t u[4]; bf16x8 v; } bfr;
            bfr.u[0] = selHi ? lo0b : lo0;
            bfr.u[1] = selHi ? lo1b : lo1;
            bfr.u[2] = selHi ? hi0b : hi0;
            bfr.u[3] = selHi ? hi1b : hi1;
#pragma unroll
            for (int df = 0; df < 4; ++df)
                acc2[nf][df] = __builtin_amdgcn_mfma_f32_16x16x32_bf16(vf[df], bfr.v, acc2[nf][df], 0, 0, 0);
        }
    }

#pragma unroll
    for (int nf = 0; nf < 2; ++nf) {
        int n = n0 + 32 * w + nf * 16 + ln;
        ushort_t* op = obuf + ((size_t)b * NPIX + n) * DIMC + h * 64;
#pragma unroll
        for (int df = 0; df < 4; ++df) {
            ushort4 v;
            v.x = f2bf(acc2[nf][df][0] * inv[nf]);
            v.y = f2bf(acc2[nf][df][1] * inv[nf]);
            v.z = f2bf(acc2[nf][df][2] * inv[nf]);
            v.w = f2bf(acc2[nf][df][3] * inv[nf]);
            *(ushort4*)&op[df * 16 + g * 4] = v;
        }
    }
}

extern "C" void kernel_launch(void* const* d_in, const int* in_sizes, int n_in,
                              void* d_out, int out_size, void* d_ws, size_t ws_size,
                              hipStream_t stream) {
    const float* x    = (const float*)d_in[0];
    const float* mask = (const float*)d_in[1];
    const float* Wq   = (const float*)d_in[2];
    const float* Wkv  = (const float*)d_in[3];
    const float* Wo   = (const float*)d_in[4];
    float* out = (float*)d_out;

    char* ws = (char*)d_ws;
    float*    md   = (float*)(ws);                         // 4 KB
    ushort_t* xt   = (ushort_t*)(ws + 4096);               // 33.55 MB
    ushort_t* wkvp = (ushort_t*)(ws + 33558528);           // 67.1 MB
    ushort_t* qbf  = wkvp;                                 // alias: convkv launch fully precedes k_g0red
    ushort_t* ktb  = (ushort_t*)(ws + 100667392);          // 0.5 MB
    ushort_t* vtb  = ktb + 524288;                         // 0.5 MB
    ushort_t* wqb  = (ushort_t*)(ws + 102764544);          // 0.5 MB
    ushort_t* wob  = wqb + 262144;                         // 0.5 MB
    float*    part = (float*)(ws + 103813120);             // 33.55 MB
    ushort_t* aob  = (ushort_t*)part;                      // alias: written after k_g0red consumed part

    k_prep<<<dim3(14338), dim3(256), 0, stream>>>(x, xt, Wkv, wkvp, mask, md, Wq, Wo, wqb, wob);

    k_convkv_mfma<<<dim3(LTOK / 128, 1024 / 128, BATCH * SPLITK), dim3(256), 0, stream>>>(xt, wkvp, part);

    k_g0red<<<dim3(3072), dim3(256), 0, stream>>>(wqb, xt, qbf, part, ktb, vtb);

    k_attn_mfma<<<dim3(NPIX / 128, BATCH * HEADS), dim3(256), 0, stream>>>(
        qbf, ktb, vtb, mask, md, aob);

    k_gemm_o<<<dim3(DIMC / 128, NPIX / 128, BATCH), dim3(256), 0, stream>>>(
        aob, (long)NPIX * DIMC, wob, out);
}

// Round 13
// 232.190 us; speedup vs baseline: 1.1572x; 1.0489x over previous
//
#include <hip/hip_runtime.h>
#include <math.h>

#define DIMC  512
#define HEADS 8
#define HD    64
#define NPIX  16384   // 128*128
#define LTOK  256     // 16*16
#define BATCH 2
#define WIMG  128
#define KVK   32768   // 512*8*8
#define EPSB  1e-8f
#define SCALEF 0.125f // 64^-0.5
#define SPLITK 16
#define KCHUNK (KVK / SPLITK)   // 2048

typedef unsigned short ushort_t;
typedef unsigned int uint_t;
using bf16x8 = __attribute__((ext_vector_type(8))) __bf16;
using f32x4  = __attribute__((ext_vector_type(4))) float;

__device__ __forceinline__ ushort_t f2bf(float f) {
    union { float f; unsigned u; } v; v.f = f;
    unsigned r = v.u + 0x7FFFu + ((v.u >> 16) & 1u);
    return (ushort_t)(r >> 16);
}
__device__ __forceinline__ uint_t pk2bf(float a, float b) {
    return (uint_t)f2bf(a) | ((uint_t)f2bf(b) << 16);
}
// async global->LDS, 16B per lane; lds base must be wave-uniform
__device__ __forceinline__ void gl16(const void* g, void* l) {
    __builtin_amdgcn_global_load_lds(
        (const __attribute__((address_space(1))) unsigned int*)g,
        (__attribute__((address_space(3))) unsigned int*)l, 16, 0, 0);
}

// ================= merged prep: xt transpose + Wkv permute + cvt + maskdown =================
// grid 12802 x 256; float4 GLOBAL loads, uint4-of-bf16 GLOBAL stores; LDS ops scalar
// (row stride 65 ≡ 1 mod 32 -> 2-way banks both phases; no LDS vector alignment issues):
//   [0,4096)      x [b][c][n] f32 -> xt [b][n][c] bf16       (LDS t[n][c])
//   [4096,12288)  Wkv [o][c][ij] -> Wkvp [o][ij*512+c] bf16  (LDS t[ij][c])
//   [12288,12800) Wq/Wo f32 -> bf16 (float4 in, 4-bf16 out)
//   [12800,12802) mask avg-pool 8x8 -> md
__global__ __launch_bounds__(256) void k_prep(
    const float* __restrict__ x, ushort_t* __restrict__ xt,
    const float* __restrict__ Wkv, ushort_t* __restrict__ Wp,
    const float* __restrict__ mask, float* __restrict__ md,
    const float* __restrict__ wq, const float* __restrict__ wo,
    ushort_t* __restrict__ wqb, ushort_t* __restrict__ wob) {
    __shared__ float t[64][65];
    const int bid = blockIdx.x;
    const int tid = threadIdx.x;
    if (bid < 4096) {
        // x[b][c0+c][n0+n] -> xt[b][n0+n][c0+c]
        int b = bid >> 11, c0 = ((bid >> 8) & 7) * 64, n0 = (bid & 255) * 64;
        const float* xb = x + ((size_t)b * DIMC + c0) * NPIX + n0;
        int tc = tid >> 4, n4 = (tid & 15) * 4;
#pragma unroll
        for (int p = 0; p < 4; ++p) {
            int c = tc + p * 16;
            float4 v = *(const float4*)&xb[(size_t)c * NPIX + n4];
            t[n4 + 0][c] = v.x;
            t[n4 + 1][c] = v.y;
            t[n4 + 2][c] = v.z;
            t[n4 + 3][c] = v.w;
        }
        __syncthreads();
        ushort_t* xtb = xt + ((size_t)b * NPIX + n0) * DIMC + c0;
        int c8 = (tid & 7) * 8;
#pragma unroll
        for (int p = 0; p < 2; ++p) {
            int nl = (tid >> 3) + p * 32;
            uint4 v;
            v.x = pk2bf(t[nl][c8 + 0], t[nl][c8 + 1]);
            v.y = pk2bf(t[nl][c8 + 2], t[nl][c8 + 3]);
            v.z = pk2bf(t[nl][c8 + 4], t[nl][c8 + 5]);
            v.w = pk2bf(t[nl][c8 + 6], t[nl][c8 + 7]);
            *(uint4*)&xtb[(size_t)nl * DIMC + c8] = v;
        }
    } else if (bid < 12288) {
        // Wkv[o][c0+c][ij] -> Wkvp[o][ij*512 + c0+c]
        int tb = bid - 4096;
        int o = tb >> 3, c0 = (tb & 7) * 64;
        const float* wb = Wkv + ((size_t)o * DIMC + c0) * 64;
        int tc = tid >> 4, ij4 = (tid & 15) * 4;
#pragma unroll
        for (int p = 0; p < 4; ++p) {
            int c = tc + p * 16;
            float4 v = *(const float4*)&wb[(size_t)c * 64 + ij4];
            t[ij4 + 0][c] = v.x;
            t[ij4 + 1][c] = v.y;
            t[ij4 + 2][c] = v.z;
            t[ij4 + 3][c] = v.w;
        }
        __syncthreads();
        ushort_t* wpb = Wp + (size_t)o * KVK + c0;
        int c8 = (tid & 7) * 8;
#pragma unroll
        for (int p = 0; p < 2; ++p) {
            int ij = (tid >> 3) + p * 32;
            uint4 v;
            v.x = pk2bf(t[ij][c8 + 0], t[ij][c8 + 1]);
            v.y = pk2bf(t[ij][c8 + 2], t[ij][c8 + 3]);
            v.z = pk2bf(t[ij][c8 + 4], t[ij][c8 + 5]);
            v.w = pk2bf(t[ij][c8 + 6], t[ij][c8 + 7]);
            *(uint4*)&wpb[(size_t)ij * DIMC + c8] = v;
        }
    } else if (bid < 12800) {
        // Wq/Wo cvt: 512 blocks * 256 threads * 4 floats = 524288 = |Wq|+|Wo|
        int i4 = ((bid - 12288) * 256 + tid) * 4;      // [0, 524288)
        if (i4 < 262144) {
            float4 v = *(const float4*)&wq[i4];
            uint2 o2; o2.x = pk2bf(v.x, v.y); o2.y = pk2bf(v.z, v.w);
            *(uint2*)&wqb[i4] = o2;
        } else {
            float4 v = *(const float4*)&wo[i4 - 262144];
            uint2 o2; o2.x = pk2bf(v.x, v.y); o2.y = pk2bf(v.z, v.w);
            *(uint2*)&wob[i4 - 262144] = o2;
        }
    } else {
        int b = bid - 12800;
        int l = tid;
        int hr = l >> 4, wr = l & 15;
        const float* mp = mask + (size_t)b * NPIX;
        float s = 0.f;
#pragma unroll
        for (int i = 0; i < 8; ++i)
#pragma unroll
            for (int j = 0; j < 8; ++j)
                s += mp[(hr * 8 + i) * WIMG + wr * 8 + j];
        md[b * LTOK + l] = s * (1.f / 64.f);
    }
}

// ================= MFMA kv conv (im2col GEMM), split-K=16, dbuf prefetch =================
// R6-proven: 3-D grid, gl16 from xt/wkvp, T2 pre-swizzled source.
__global__ __launch_bounds__(256) void k_convkv_mfma(
    const ushort_t* __restrict__ xt, const ushort_t* __restrict__ Wp,
    float* __restrict__ part) {
    __shared__ ushort_t Asm[2][128 * 64];
    __shared__ ushort_t Bsm[2][128 * 64];
    const int tid = threadIdx.x;
    const int w = tid >> 6, lane = tid & 63;
    const int wm = w >> 1, wn = w & 1;
    const int lr = lane & 15, lg = lane >> 4;
    const int z = blockIdx.z;
    const int b = z >> 4, ks = z & 15;
    const int m0 = blockIdx.y * 128, n0 = blockIdx.x * 128;
    const ushort_t* xtb = xt + (size_t)b * NPIX * DIMC;
    const int kbeg = ks * KCHUNK;

    f32x4 acc[4][4];
    const f32x4 zz = {0.f, 0.f, 0.f, 0.f};
#pragma unroll
    for (int i = 0; i < 4; ++i)
#pragma unroll
        for (int j = 0; j < 4; ++j) acc[i][j] = zz;

#define STAGE_KV(buf, k0) do {                                               \
    _Pragma("unroll")                                                        \
    for (int r = 0; r < 4; ++r) {                                            \
        int slot = r * 256 + tid;                                            \
        int m = slot >> 3, kb = slot & 7;                                    \
        int kbs = kb ^ (m & 7);                                              \
        gl16(Wp + (size_t)(m0 + m) * KVK + (k0) + kbs * 8,                   \
             &Asm[buf][(size_t)(r * 256 + w * 64) * 8]);                     \
    }                                                                        \
    _Pragma("unroll")                                                        \
    for (int r = 0; r < 4; ++r) {                                            \
        int slot = r * 256 + tid;                                            \
        int nn = slot >> 3, kb = slot & 7;                                   \
        int l = n0 + nn, hr = l >> 4, wr = l & 15;                           \
        int kp = (k0) + (kb ^ (nn & 7)) * 8;                                 \
        int ij = kp >> 9, ck = kp & 511;                                     \
        int ii = ij >> 3, jj = ij & 7;                                       \
        gl16(xtb + (size_t)((hr * 8 + ii) * WIMG + wr * 8 + jj) * DIMC + ck, \
             &Bsm[buf][(size_t)(r * 256 + w * 64) * 8]);                     \
    }                                                                        \
} while (0)

    STAGE_KV(0, kbeg);
    __syncthreads();
    int cur = 0;
#pragma unroll 1
    for (int t = 0; t < KCHUNK / 64; ++t) {
        if (t < KCHUNK / 64 - 1) STAGE_KV(cur ^ 1, kbeg + (t + 1) * 64);
#pragma unroll
        for (int kk = 0; kk < 2; ++kk) {
            bf16x8 af[4], bfr[4];
#pragma unroll
            for (int i = 0; i < 4; ++i) {
                int row = wm * 64 + i * 16 + lr;
                af[i] = *(const bf16x8*)&Asm[cur][(size_t)(row * 8 + ((kk * 4 + lg) ^ (row & 7))) * 8];
            }
#pragma unroll
            for (int j = 0; j < 4; ++j) {
                int row = wn * 64 + j * 16 + lr;
                bfr[j] = *(const bf16x8*)&Bsm[cur][(size_t)(row * 8 + ((kk * 4 + lg) ^ (row & 7))) * 8];
            }
#pragma unroll
            for (int i = 0; i < 4; ++i)
#pragma unroll
                for (int j = 0; j < 4; ++j)
                    acc[i][j] = __builtin_amdgcn_mfma_f32_16x16x32_bf16(af[i], bfr[j], acc[i][j], 0, 0, 0);
        }
        if (t < KCHUNK / 64 - 1) {
            __syncthreads();
            cur ^= 1;
        }
    }
#undef STAGE_KV

    float* P = part + (size_t)z * (LTOK * 1024);
#pragma unroll
    for (int i = 0; i < 4; ++i) {
        int o0 = m0 + wm * 64 + i * 16 + lg * 4;
#pragma unroll
        for (int j = 0; j < 4; ++j) {
            int l = n0 + wn * 64 + j * 16 + lr;
            *(f32x4*)&P[(size_t)l * 1024 + o0] = acc[i][j];
        }
    }
}

// ================= merged: q-projection GEMM + kv reduce =================
__global__ __launch_bounds__(256) void k_g0red(
    const ushort_t* __restrict__ wqb, const ushort_t* __restrict__ xt,
    ushort_t* __restrict__ qbf,
    const float* __restrict__ part,
    ushort_t* __restrict__ kt, ushort_t* __restrict__ vt) {
    __shared__ ushort_t Asm[2][128 * 64];
    __shared__ ushort_t Bsm[2][128 * 64];
    const int bid = blockIdx.x;
    if (bid < 1024) {
        const int tid = threadIdx.x;
        const int w = tid >> 6, lane = tid & 63;
        const int wm = w >> 1, wn = w & 1;
        const int lr = lane & 15, lg = lane >> 4;
        const int c0 = (bid & 127) * 128;          // over NPIX
        const int m0 = ((bid >> 7) & 3) * 128;     // over DIMC (Wq rows)
        const int bz = bid >> 9;
        const ushort_t* Ab = wqb;
        const ushort_t* Bb = xt + (size_t)bz * NPIX * DIMC;

        f32x4 acc[4][4];
        const f32x4 zz = {0.f, 0.f, 0.f, 0.f};
#pragma unroll
        for (int i = 0; i < 4; ++i)
#pragma unroll
            for (int j = 0; j < 4; ++j) acc[i][j] = zz;

#define STAGE_G0(buf, k0) do {                                               \
    _Pragma("unroll")                                                        \
    for (int r = 0; r < 4; ++r) {                                            \
        int slot = r * 256 + tid;                                            \
        int m = slot >> 3, kb = slot & 7;                                    \
        int kbs = kb ^ (m & 7);                                              \
        gl16(Ab + (size_t)(m0 + m) * DIMC + (k0) + kbs * 8,                  \
             &Asm[buf][(size_t)(r * 256 + w * 64) * 8]);                     \
    }                                                                        \
    _Pragma("unroll")                                                        \
    for (int r = 0; r < 4; ++r) {                                            \
        int slot = r * 256 + tid;                                            \
        int m = slot >> 3, kb = slot & 7;                                    \
        int kbs = kb ^ (m & 7);                                              \
        gl16(Bb + (size_t)(c0 + m) * DIMC + (k0) + kbs * 8,                  \
             &Bsm[buf][(size_t)(r * 256 + w * 64) * 8]);                     \
    }                                                                        \
} while (0)

        STAGE_G0(0, 0);
        __syncthreads();
        int cur = 0;
#pragma unroll 1
        for (int t = 0; t < 8; ++t) {
            if (t < 7) STAGE_G0(cur ^ 1, (t + 1) * 64);
#pragma unroll
            for (int kk = 0; kk < 2; ++kk) {
                bf16x8 af[4], bfr[4];
#pragma unroll
                for (int i = 0; i < 4; ++i) {
                    int row = wm * 64 + i * 16 + lr;
                    af[i] = *(const bf16x8*)&Asm[cur][(size_t)(row * 8 + ((kk * 4 + lg) ^ (row & 7))) * 8];
                }
#pragma unroll
                for (int j = 0; j < 4; ++j) {
                    int row = wn * 64 + j * 16 + lr;
                    bfr[j] = *(const bf16x8*)&Bsm[cur][(size_t)(row * 8 + ((kk * 4 + lg) ^ (row & 7))) * 8];
                }
#pragma unroll
                for (int i = 0; i < 4; ++i)
#pragma unroll
                    for (int j = 0; j < 4; ++j)
                        acc[i][j] = __builtin_amdgcn_mfma_f32_16x16x32_bf16(af[i], bfr[j], acc[i][j], 0, 0, 0);
            }
            if (t < 7) {
                __syncthreads();
                cur ^= 1;
            }
        }
#undef STAGE_G0

        ushort_t* q = qbf + (size_t)bz * ((size_t)NPIX * DIMC);
#pragma unroll
        for (int i = 0; i < 4; ++i) {
            int d0 = m0 + wm * 64 + i * 16 + lg * 4;
#pragma unroll
            for (int j = 0; j < 4; ++j) {
                int n = c0 + wn * 64 + j * 16 + lr;
                ushort4 v;
                v.x = f2bf(acc[i][j][0]); v.y = f2bf(acc[i][j][1]);
                v.z = f2bf(acc[i][j][2]); v.w = f2bf(acc[i][j][3]);
                *(ushort4*)&q[(size_t)n * DIMC + d0] = v;
            }
        }
    } else {
        int idx = (bid - 1024) * 256 + threadIdx.x;   // [0, 2*256*1024)
        int o = idx & 1023;
        int rest = idx >> 10;
        int l = rest & 255, b = rest >> 8;
        float s = 0.f;
#pragma unroll
        for (int ks = 0; ks < SPLITK; ++ks)
            s += part[(size_t)(b * SPLITK + ks) * (LTOK * 1024) + (size_t)l * 1024 + o];
        int h = (o >> 6) & 7, d = o & 63;
        if (o < 512)
            kt[(((size_t)b * 8 + h) * 256 + l) * 64 + d] = f2bf(s);
        else
            vt[(((size_t)b * 8 + h) * 64 + d) * 256 + l] = f2bf(s);
    }
}

// ================= output-projection GEMM =================
__global__ __launch_bounds__(256) void k_gemm_o(
    const ushort_t* __restrict__ A, long sA,
    const ushort_t* __restrict__ B,
    float* __restrict__ Yv) {
    __shared__ ushort_t Asm[2][128 * 64];
    __shared__ ushort_t Bsm[2][128 * 64];
    const int tid = threadIdx.x;
    const int w = tid >> 6, lane = tid & 63;
    const int wm = w >> 1, wn = w & 1;
    const int lr = lane & 15, lg = lane >> 4;
    const int bz = blockIdx.z;
    const int m0 = blockIdx.y * 128, c0 = blockIdx.x * 128;
    const ushort_t* Ab = A + (size_t)bz * sA;
    const ushort_t* Bb = B;

    f32x4 acc[4][4];
    const f32x4 zz = {0.f, 0.f, 0.f, 0.f};
#pragma unroll
    for (int i = 0; i < 4; ++i)
#pragma unroll
        for (int j = 0; j < 4; ++j) acc[i][j] = zz;

#define STAGE_O(buf, k0) do {                                                \
    _Pragma("unroll")                                                        \
    for (int r = 0; r < 4; ++r) {                                            \
        int slot = r * 256 + tid;                                            \
        int m = slot >> 3, kb = slot & 7;                                    \
        int kbs = kb ^ (m & 7);                                              \
        gl16(Ab + (size_t)(m0 + m) * DIMC + (k0) + kbs * 8,                  \
             &Asm[buf][(size_t)(r * 256 + w * 64) * 8]);                     \
    }                                                                        \
    _Pragma("unroll")                                                        \
    for (int r = 0; r < 4; ++r) {                                            \
        int slot = r * 256 + tid;                                            \
        int m = slot >> 3, kb = slot & 7;                                    \
        int kbs = kb ^ (m & 7);                                              \
        gl16(Bb + (size_t)(c0 + m) * DIMC + (k0) + kbs * 8,                  \
             &Bsm[buf][(size_t)(r * 256 + w * 64) * 8]);                     \
    }                                                                        \
} while (0)

    STAGE_O(0, 0);
    __syncthreads();
    int cur = 0;
#pragma unroll 1
    for (int t = 0; t < 8; ++t) {
        if (t < 7) STAGE_O(cur ^ 1, (t + 1) * 64);
#pragma unroll
        for (int kk = 0; kk < 2; ++kk) {
            bf16x8 af[4], bfr[4];
#pragma unroll
            for (int i = 0; i < 4; ++i) {
                int row = wm * 64 + i * 16 + lr;
                af[i] = *(const bf16x8*)&Asm[cur][(size_t)(row * 8 + ((kk * 4 + lg) ^ (row & 7))) * 8];
            }
#pragma unroll
            for (int j = 0; j < 4; ++j) {
                int row = wn * 64 + j * 16 + lr;
                bfr[j] = *(const bf16x8*)&Bsm[cur][(size_t)(row * 8 + ((kk * 4 + lg) ^ (row & 7))) * 8];
            }
#pragma unroll
            for (int i = 0; i < 4; ++i)
#pragma unroll
                for (int j = 0; j < 4; ++j)
                    acc[i][j] = __builtin_amdgcn_mfma_f32_16x16x32_bf16(af[i], bfr[j], acc[i][j], 0, 0, 0);
        }
        if (t < 7) {
            __syncthreads();
            cur ^= 1;
        }
    }
#undef STAGE_O

    float* O = Yv + (size_t)bz * ((size_t)DIMC * NPIX);
#pragma unroll
    for (int i = 0; i < 4; ++i) {
        int n0r = m0 + wm * 64 + i * 16 + lg * 4;
#pragma unroll
        for (int j = 0; j < 4; ++j) {
            int o = c0 + wn * 64 + j * 16 + lr;
            *(f32x4*)&O[(size_t)o * NPIX + n0r] = acc[i][j];
        }
    }
}

// ================= MFMA fused attention (R6 proven version) =================
__global__ __launch_bounds__(256, 2) void k_attn_mfma(
    const ushort_t* __restrict__ qbf, const ushort_t* __restrict__ kt,
    const ushort_t* __restrict__ vt, const float* __restrict__ mask,
    const float* __restrict__ md, ushort_t* __restrict__ obuf) {
    __shared__ ushort_t Qs[128 * 64];   // 16KB, rows 128B, 8 slots of 16B, XOR-swizzled
    __shared__ ushort_t Ks[256 * 64];   // 32KB
    __shared__ ushort_t Vs[64 * 256];   // 32KB, rows 512B, 32 slots

    const int tid = threadIdx.x;
    const int w = tid >> 6, lane = tid & 63;
    const int g = lane >> 4, ln = lane & 15;
    const int bh = blockIdx.y, b = bh >> 3, h = bh & 7;
    const int bb = bh & 1;              // bias batch quirk: (b*8+h) % 2
    const int n0 = blockIdx.x * 128;

    {
        const ushort_t* src = qbf + ((size_t)b * NPIX + n0) * DIMC + h * 64;
#pragma unroll
        for (int p = 0; p < 4; ++p) {
            int id = p * 256 + tid;
            int r = id >> 3, s = id & 7;
            uint4 v = *(const uint4*)(src + (size_t)r * DIMC + s * 8);
            *(uint4*)&Qs[(r * 8 + (s ^ (r & 7))) * 8] = v;
        }
    }
    {
        const ushort_t* src = kt + (size_t)bh * 256 * 64;
#pragma unroll
        for (int p = 0; p < 8; ++p) {
            int id = p * 256 + tid;
            int r = id >> 3, s = id & 7;
            uint4 v = *(const uint4*)(src + r * 64 + s * 8);
            *(uint4*)&Ks[(r * 8 + (s ^ (r & 7))) * 8] = v;
        }
    }
    {
        const ushort_t* src = vt + (size_t)bh * 64 * 256;
#pragma unroll
        for (int p = 0; p < 8; ++p) {
            int id = p * 256 + tid;
            int r = id >> 5, s = id & 31;
            uint4 v = *(const uint4*)(src + r * 256 + s * 8);
            *(uint4*)&Vs[(r * 32 + (s ^ (r & 7))) * 8] = v;
        }
    }
    __syncthreads();

    f32x4 acc[2][16];
    const f32x4 zz = {0.f, 0.f, 0.f, 0.f};
#pragma unroll
    for (int nf = 0; nf < 2; ++nf)
#pragma unroll
        for (int f = 0; f < 16; ++f) acc[nf][f] = zz;

    bf16x8 qf[2][2];
#pragma unroll
    for (int nf = 0; nf < 2; ++nf)
#pragma unroll
        for (int kk = 0; kk < 2; ++kk) {
            int nl = 32 * w + nf * 16 + ln;
            qf[nf][kk] = *(const bf16x8*)&Qs[(nl * 8 + ((kk * 4 + g) ^ (nl & 7))) * 8];
        }
#pragma unroll
    for (int f = 0; f < 16; ++f) {
#pragma unroll
        for (int kk = 0; kk < 2; ++kk) {
            int l = f * 16 + ln;
            bf16x8 kf = *(const bf16x8*)&Ks[(l * 8 + ((kk * 4 + g) ^ (l & 7))) * 8];
            acc[0][f] = __builtin_amdgcn_mfma_f32_16x16x32_bf16(kf, qf[0][kk], acc[0][f], 0, 0, 0);
            acc[1][f] = __builtin_amdgcn_mfma_f32_16x16x32_bf16(kf, qf[1][kk], acc[1][f], 0, 0, 0);
        }
    }

    float inv[2];
    uint2 pb[2][16];
#pragma unroll
    for (int nf = 0; nf < 2; ++nf) {
        float mval = mask[(size_t)bb * NPIX + n0 + 32 * w + nf * 16 + ln];
        float mx = -1e30f;
#pragma unroll
        for (int f = 0; f < 16; ++f) {
            float4 md4 = *(const float4*)&md[bb * LTOK + f * 16 + g * 4];
            float s0 = (acc[nf][f][0] + __logf(mval * md4.x + EPSB)) * SCALEF;
            float s1 = (acc[nf][f][1] + __logf(mval * md4.y + EPSB)) * SCALEF;
            float s2 = (acc[nf][f][2] + __logf(mval * md4.z + EPSB)) * SCALEF;
            float s3 = (acc[nf][f][3] + __logf(mval * md4.w + EPSB)) * SCALEF;
            acc[nf][f][0] = s0; acc[nf][f][1] = s1;
            acc[nf][f][2] = s2; acc[nf][f][3] = s3;
            mx = fmaxf(mx, fmaxf(fmaxf(s0, s1), fmaxf(s2, s3)));
        }
        mx = fmaxf(mx, __shfl_xor(mx, 16));
        mx = fmaxf(mx, __shfl_xor(mx, 32));
        float sum = 0.f;
#pragma unroll
        for (int f = 0; f < 16; ++f) {
            float p0 = __expf(acc[nf][f][0] - mx);
            float p1 = __expf(acc[nf][f][1] - mx);
            float p2 = __expf(acc[nf][f][2] - mx);
            float p3 = __expf(acc[nf][f][3] - mx);
            sum += (p0 + p1) + (p2 + p3);
            pb[nf][f].x = pk2bf(p0, p1);
            pb[nf][f].y = pk2bf(p2, p3);
        }
        sum += __shfl_xor(sum, 16);
        sum += __shfl_xor(sum, 32);
        inv[nf] = 1.f / sum;
    }

    f32x4 acc2[2][4];
#pragma unroll
    for (int nf = 0; nf < 2; ++nf)
#pragma unroll
        for (int df = 0; df < 4; ++df) acc2[nf][df] = zz;

    const int srcLo = ((g & 1) << 5) + ln;
    const bool selHi = (g >> 1);
#pragma unroll
    for (int ks = 0; ks < 8; ++ks) {
        bf16x8 vf[4];
#pragma unroll
        for (int df = 0; df < 4; ++df) {
            int d = df * 16 + ln;
            vf[df] = *(const bf16x8*)&Vs[(d * 32 + ((ks * 4 + g) ^ (d & 7))) * 8];
        }
#pragma unroll
        for (int nf = 0; nf < 2; ++nf) {
            uint_t e0 = pb[nf][2 * ks].x,     e1 = pb[nf][2 * ks].y;
            uint_t o0 = pb[nf][2 * ks + 1].x, o1 = pb[nf][2 * ks + 1].y;
            uint_t lo0 = __shfl((int)e0, srcLo), lo1 = __shfl((int)e1, srcLo);
            uint_t lo0b = __shfl((int)o0, srcLo), lo1b = __shfl((int)o1, srcLo);
            uint_t hi0 = __shfl((int)e0, srcLo + 16), hi1 = __shfl((int)e1, srcLo + 16);
            uint_t hi0b = __shfl((int)o0, srcLo + 16), hi1b = __shfl((int)o1, srcLo + 16);
            union { uint_t u[4]; bf16x8 v; } bfr;
            bfr.u[0] = selHi ? lo0b : lo0;
            bfr.u[1] = selHi ? lo1b : lo1;
            bfr.u[2] = selHi ? hi0b : hi0;
            bfr.u[3] = selHi ? hi1b : hi1;
#pragma unroll
            for (int df = 0; df < 4; ++df)
                acc2[nf][df] = __builtin_amdgcn_mfma_f32_16x16x32_bf16(vf[df], bfr.v, acc2[nf][df], 0, 0, 0);
        }
    }

#pragma unroll
    for (int nf = 0; nf < 2; ++nf) {
        int n = n0 + 32 * w + nf * 16 + ln;
        ushort_t* op = obuf + ((size_t)b * NPIX + n) * DIMC + h * 64;
#pragma unroll
        for (int df = 0; df < 4; ++df) {
            ushort4 v;
            v.x = f2bf(acc2[nf][df][0] * inv[nf]);
            v.y = f2bf(acc2[nf][df][1] * inv[nf]);
            v.z = f2bf(acc2[nf][df][2] * inv[nf]);
            v.w = f2bf(acc2[nf][df][3] * inv[nf]);
            *(ushort4*)&op[df * 16 + g * 4] = v;
        }
    }
}

extern "C" void kernel_launch(void* const* d_in, const int* in_sizes, int n_in,
                              void* d_out, int out_size, void* d_ws, size_t ws_size,
                              hipStream_t stream) {
    const float* x    = (const float*)d_in[0];
    const float* mask = (const float*)d_in[1];
    const float* Wq   = (const float*)d_in[2];
    const float* Wkv  = (const float*)d_in[3];
    const float* Wo   = (const float*)d_in[4];
    float* out = (float*)d_out;

    char* ws = (char*)d_ws;
    float*    md   = (float*)(ws);                         // 4 KB
    ushort_t* xt   = (ushort_t*)(ws + 4096);               // 33.55 MB
    ushort_t* wkvp = (ushort_t*)(ws + 33558528);           // 67.1 MB
    ushort_t* qbf  = wkvp;                                 // alias: convkv launch fully precedes k_g0red
    ushort_t* ktb  = (ushort_t*)(ws + 100667392);          // 0.5 MB
    ushort_t* vtb  = ktb + 524288;                         // 0.5 MB
    ushort_t* wqb  = (ushort_t*)(ws + 102764544);          // 0.5 MB
    ushort_t* wob  = wqb + 262144;                         // 0.5 MB
    float*    part = (float*)(ws + 103813120);             // 33.55 MB
    ushort_t* aob  = (ushort_t*)part;                      // alias: written after k_g0red consumed part

    k_prep<<<dim3(12802), dim3(256), 0, stream>>>(x, xt, Wkv, wkvp, mask, md, Wq, Wo, wqb, wob);

    k_convkv_mfma<<<dim3(LTOK / 128, 1024 / 128, BATCH * SPLITK), dim3(256), 0, stream>>>(xt, wkvp, part);

    k_g0red<<<dim3(3072), dim3(256), 0, stream>>>(wqb, xt, qbf, part, ktb, vtb);

    k_attn_mfma<<<dim3(NPIX / 128, BATCH * HEADS), dim3(256), 0, stream>>>(
        qbf, ktb, vtb, mask, md, aob);

    k_gemm_o<<<dim3(DIMC / 128, NPIX / 128, BATCH), dim3(256), 0, stream>>>(
        aob, (long)NPIX * DIMC, wob, out);
}